// Round 13
// baseline (194.619 us; speedup 1.0000x reference)
//
#include <hip/hip_runtime.h>
#include <hip/hip_bf16.h>
#include <math.h>

#define N_NODES 50000
#define NPAD 50048                      // 391 * 128
#define N_EDGES 800000
#define NEG_SLOPE 0.2f
#define NBUCK ((N_NODES + 255) / 256)   // 196 buckets of 256 dsts
#define CCHUNK 4096
#define DCAP 8192

__device__ inline float lrelu(float x) { return fmaxf(x, NEG_SLOPE * x); }

__device__ inline unsigned bf16rne(float f) {
    unsigned u = __float_as_uint(f);
    return (u + 0x7fffu + ((u >> 16) & 1u)) >> 16;
}
__device__ inline float bf2f(unsigned h) { return __uint_as_float(h << 16); }

// ---------------- CSR build: LDS-staged bucket sort ----------------
__global__ void zerobuf_kernel(int* __restrict__ p) {
    int i = threadIdx.x;
    if (i < NBUCK) p[i] = 0;
}

__global__ __launch_bounds__(256) void bucketcount_kernel(const int* __restrict__ ei,
                                                          int* __restrict__ gbcnt) {
    __shared__ int lc[NBUCK];
    for (int i = threadIdx.x; i < NBUCK; i += 256) lc[i] = 0;
    __syncthreads();
    int stride = gridDim.x * 256;
    for (int e = blockIdx.x * 256 + threadIdx.x; e < N_EDGES; e += stride)
        atomicAdd(&lc[ei[N_EDGES + e] >> 8], 1);
    __syncthreads();
    for (int i = threadIdx.x; i < NBUCK; i += 256)
        if (lc[i]) atomicAdd(&gbcnt[i], lc[i]);
}

__global__ __launch_bounds__(256) void bucketscan_kernel(const int* __restrict__ gbcnt,
                                                         int* __restrict__ bbase,
                                                         int* __restrict__ bcur) {
    __shared__ int ss[256];
    int t = threadIdx.x;
    int v = (t < NBUCK) ? gbcnt[t] : 0;
    ss[t] = v;
    __syncthreads();
    for (int d = 1; d < 256; d <<= 1) {
        int u = (t >= d) ? ss[t - d] : 0;
        __syncthreads();
        ss[t] += u;
        __syncthreads();
    }
    int excl = ss[t] - v;
    if (t < NBUCK) { bbase[t] = excl; bcur[t] = excl; }
    if (t == 0) bbase[NBUCK] = N_EDGES;
}

__global__ __launch_bounds__(256) void bucketscatter_kernel(const int* __restrict__ ei,
                                                            int* __restrict__ bcur,
                                                            int2* __restrict__ bpairs) {
    __shared__ int cnt[NBUCK], startl[NBUCK], baseg[NBUCK], cur2[NBUCK];
    __shared__ int ss[256];
    __shared__ int2 stage[CCHUNK];
    int t = threadIdx.x;
    int e0 = blockIdx.x * CCHUNK;
    int nume = min(CCHUNK, N_EDGES - e0);
    for (int i = t; i < NBUCK; i += 256) { cnt[i] = 0; cur2[i] = 0; }
    __syncthreads();
    int src[CCHUNK / 256], dst[CCHUNK / 256];
    #pragma unroll
    for (int j = 0; j < CCHUNK / 256; ++j) {
        int idx = t + j * 256;
        if (idx < nume) {
            src[j] = ei[e0 + idx];
            dst[j] = ei[N_EDGES + e0 + idx];
            atomicAdd(&cnt[dst[j] >> 8], 1);
        } else dst[j] = -1;
    }
    __syncthreads();
    {
        int v = (t < NBUCK) ? cnt[t] : 0;
        ss[t] = v;
        __syncthreads();
        for (int d = 1; d < 256; d <<= 1) {
            int u = (t >= d) ? ss[t - d] : 0;
            __syncthreads();
            ss[t] += u;
            __syncthreads();
        }
        if (t < NBUCK) startl[t] = ss[t] - v;
    }
    __syncthreads();
    if (t < NBUCK && cnt[t] > 0) baseg[t] = atomicAdd(&bcur[t], cnt[t]);
    __syncthreads();
    #pragma unroll
    for (int j = 0; j < CCHUNK / 256; ++j) {
        if (dst[j] >= 0) {
            int b = dst[j] >> 8;
            int slot = startl[b] + atomicAdd(&cur2[b], 1);
            stage[slot] = make_int2(src[j], dst[j]);
        }
    }
    __syncthreads();
    for (int i = t; i < nume; i += 256) {
        int2 p = stage[i];
        int b = p.y >> 8;
        bpairs[baseg[b] + (i - startl[b])] = p;
    }
}

__global__ __launch_bounds__(256) void csrfinalize_kernel(const int2* __restrict__ bpairs,
                                                          const int* __restrict__ bbase,
                                                          int* __restrict__ ptr,
                                                          int* __restrict__ csr) {
    __shared__ int cnt[256], excl[256], cur[256];
    __shared__ int ss[256];
    __shared__ int2 P[DCAP];
    int b = blockIdx.x, t = threadIdx.x;
    int bb = bbase[b], be = bbase[b + 1];
    int n = be - bb;
    int d0 = b << 8;
    int dmax = min(256, N_NODES - d0);
    bool fits = (n <= DCAP);
    cnt[t] = 0; cur[t] = 0;
    __syncthreads();
    for (int i = t; i < n; i += 256) {
        int2 p = bpairs[bb + i];
        if (fits) P[i] = p;
        atomicAdd(&cnt[p.y & 255], 1);
    }
    __syncthreads();
    {
        int v = cnt[t];
        ss[t] = v;
        __syncthreads();
        for (int d = 1; d < 256; d <<= 1) {
            int u = (t >= d) ? ss[t - d] : 0;
            __syncthreads();
            ss[t] += u;
            __syncthreads();
        }
        excl[t] = ss[t] - v;
    }
    __syncthreads();
    if (t < dmax) ptr[d0 + t] = bb + excl[t];
    if (b == NBUCK - 1 && t == 0) ptr[N_NODES] = N_EDGES;
    for (int i = t; i < n; i += 256) {
        int2 p = fits ? P[i] : bpairs[bb + i];
        int ld = p.y & 255;
        int pos = bb + excl[ld] + atomicAdd(&cur[ld], 1);
        csr[pos] = p.x;
    }
}

// ---------------- prep: bf16-split conversions ----------------
__global__ __launch_bounds__(256) void convx_kernel(const float* __restrict__ x,
                                                    unsigned short* __restrict__ xh,
                                                    unsigned short* __restrict__ xl,
                                                    unsigned short* __restrict__ x2h,
                                                    unsigned short* __restrict__ x2l) {
    int q = blockIdx.x * 256 + threadIdx.x;
    if (q >= NPAD * 128 / 4) return;
    int e = q * 4;
    int row = e >> 7;
    float vv[4] = {0.f, 0.f, 0.f, 0.f};
    if (row < N_NODES) {
        float4 v = *(const float4*)(x + e);
        vv[0] = v.x; vv[1] = v.y; vv[2] = v.z; vv[3] = v.w;
    }
    ushort4 hh, ll;
    unsigned h0 = bf16rne(vv[0]), h1 = bf16rne(vv[1]), h2 = bf16rne(vv[2]), h3 = bf16rne(vv[3]);
    hh.x = h0; hh.y = h1; hh.z = h2; hh.w = h3;
    ll.x = bf16rne(vv[0] - bf2f(h0));
    ll.y = bf16rne(vv[1] - bf2f(h1));
    ll.z = bf16rne(vv[2] - bf2f(h2));
    ll.w = bf16rne(vv[3] - bf2f(h3));
    *(ushort4*)(xh + e) = hh;
    *(ushort4*)(xl + e) = ll;
    if (row >= N_NODES) {
        ushort4 z = {0, 0, 0, 0};
        *(ushort4*)(x2h + e) = z;
        *(ushort4*)(x2l + e) = z;
    }
}

__global__ __launch_bounds__(256) void convw_kernel(const float* __restrict__ W,
                                                    unsigned short* __restrict__ wth,
                                                    unsigned short* __restrict__ wtl) {
    int idx = blockIdx.x * 256 + threadIdx.x;
    if (idx >= 128 * 128) return;
    int c = idx >> 7, k = idx & 127;
    float v = W[(size_t)k * 128 + c];
    unsigned h = bf16rne(v);
    wth[idx] = (unsigned short)h;
    wtl[idx] = (unsigned short)bf16rne(v - bf2f(h));
}

// ---- MFMA GEMM (bf16x2 split, ~f32 accurate) + attention-logit epilogue ----
template <int H>
__global__ __launch_bounds__(256) void gemm_mfma_kernel(const unsigned short* __restrict__ Ah,
                                                        const unsigned short* __restrict__ Al,
                                                        const unsigned short* __restrict__ Bh,
                                                        const unsigned short* __restrict__ Bl,
                                                        const float* __restrict__ asrc,
                                                        const float* __restrict__ adst,
                                                        unsigned short* __restrict__ Hb,
                                                        float* __restrict__ als,
                                                        float* __restrict__ ald,
                                                        int nrows) {
    using bf16x8 = __attribute__((ext_vector_type(8))) short;
    using f32x4  = __attribute__((ext_vector_type(4))) float;
    const int lane = threadIdx.x & 63;
    const int wv = threadIdx.x >> 6;
    const int l15 = lane & 15;
    const int g = lane >> 4;
    const int lk = g * 8;
    const int rowbase = blockIdx.x * 128 + wv * 32;

    f32x4 acc[2][8];
    #pragma unroll
    for (int rt = 0; rt < 2; ++rt)
        #pragma unroll
        for (int ct = 0; ct < 8; ++ct) acc[rt][ct] = (f32x4){0.f, 0.f, 0.f, 0.f};

    #pragma unroll
    for (int kc = 0; kc < 4; ++kc) {
        const int ko = kc * 32 + lk;
        bf16x8 ah0 = *(const bf16x8*)(Ah + (size_t)(rowbase + l15) * 128 + ko);
        bf16x8 ah1 = *(const bf16x8*)(Ah + (size_t)(rowbase + 16 + l15) * 128 + ko);
        bf16x8 al0 = *(const bf16x8*)(Al + (size_t)(rowbase + l15) * 128 + ko);
        bf16x8 al1 = *(const bf16x8*)(Al + (size_t)(rowbase + 16 + l15) * 128 + ko);
        #pragma unroll
        for (int ct = 0; ct < 8; ++ct) {
            bf16x8 bh = *(const bf16x8*)(Bh + (size_t)(ct * 16 + l15) * 128 + ko);
            bf16x8 bl = *(const bf16x8*)(Bl + (size_t)(ct * 16 + l15) * 128 + ko);
            acc[0][ct] = __builtin_amdgcn_mfma_f32_16x16x32_bf16(ah0, bh, acc[0][ct], 0, 0, 0);
            acc[0][ct] = __builtin_amdgcn_mfma_f32_16x16x32_bf16(ah0, bl, acc[0][ct], 0, 0, 0);
            acc[0][ct] = __builtin_amdgcn_mfma_f32_16x16x32_bf16(al0, bh, acc[0][ct], 0, 0, 0);
            acc[1][ct] = __builtin_amdgcn_mfma_f32_16x16x32_bf16(ah1, bh, acc[1][ct], 0, 0, 0);
            acc[1][ct] = __builtin_amdgcn_mfma_f32_16x16x32_bf16(ah1, bl, acc[1][ct], 0, 0, 0);
            acc[1][ct] = __builtin_amdgcn_mfma_f32_16x16x32_bf16(al1, bh, acc[1][ct], 0, 0, 0);
        }
    }

    float as8[8], ad8[8];
    #pragma unroll
    for (int ct = 0; ct < 8; ++ct) { as8[ct] = asrc[ct * 16 + l15]; ad8[ct] = adst[ct * 16 + l15]; }

    #pragma unroll
    for (int rt = 0; rt < 2; ++rt) {
        #pragma unroll
        for (int ct = 0; ct < 8; ++ct) {
            #pragma unroll
            for (int j = 0; j < 4; ++j) {
                int row = rowbase + rt * 16 + g * 4 + j;
                if (row < nrows)
                    Hb[(size_t)row * 128 + ct * 16 + l15] = (unsigned short)bf16rne(acc[rt][ct][j]);
            }
        }
        #pragma unroll
        for (int j = 0; j < 4; ++j) {
            int row = rowbase + rt * 16 + g * 4 + j;
            if (H == 2) {
                float sp0 = 0.f, sp1 = 0.f, dp0 = 0.f, dp1 = 0.f;
                #pragma unroll
                for (int ct = 0; ct < 4; ++ct) { sp0 += acc[rt][ct][j] * as8[ct]; dp0 += acc[rt][ct][j] * ad8[ct]; }
                #pragma unroll
                for (int ct = 4; ct < 8; ++ct) { sp1 += acc[rt][ct][j] * as8[ct]; dp1 += acc[rt][ct][j] * ad8[ct]; }
                #pragma unroll
                for (int off = 1; off < 16; off <<= 1) {
                    sp0 += __shfl_xor(sp0, off); sp1 += __shfl_xor(sp1, off);
                    dp0 += __shfl_xor(dp0, off); dp1 += __shfl_xor(dp1, off);
                }
                if (l15 == 0 && row < nrows) {
                    als[(size_t)row * 2]     = sp0; als[(size_t)row * 2 + 1] = sp1;
                    ald[(size_t)row * 2]     = dp0; ald[(size_t)row * 2 + 1] = dp1;
                }
            } else {
                float sp = 0.f, dp = 0.f;
                #pragma unroll
                for (int ct = 0; ct < 8; ++ct) { sp += acc[rt][ct][j] * as8[ct]; dp += acc[rt][ct][j] * ad8[ct]; }
                #pragma unroll
                for (int off = 1; off < 16; off <<= 1) {
                    sp += __shfl_xor(sp, off); dp += __shfl_xor(dp, off);
                }
                if (l15 == 0 && row < nrows) { als[row] = sp; ald[row] = dp; }
            }
        }
    }
}

// ---- fused softmax+gather v4: quarter-split 16B gathers + 4-deep ILP ----
// Phase B: 16 edges/iter; 4 statically-unrolled slots (one edge per quarter each),
// LDS p/src prefetched to regs, 4 independent uint4 gathers in flight.
// s_p padded to 68 so head0/head1 rows land in different banks.
template <int H, int DO_ELU, int BSPLIT>
__global__ __launch_bounds__(256) void aggregate_kernel(const unsigned short* __restrict__ Hb,
                                                        const float* __restrict__ als,
                                                        const float* __restrict__ aldv,
                                                        const int* __restrict__ ptr,
                                                        const int* __restrict__ csr,
                                                        const float* __restrict__ bias,
                                                        float* __restrict__ out,
                                                        unsigned short* __restrict__ oh,
                                                        unsigned short* __restrict__ ol) {
    __shared__ int   s_src[4][64];
    __shared__ float s_p[4][H][68];
    const int w = threadIdx.x >> 6;
    const int lane = threadIdx.x & 63;
    const int d = blockIdx.x * 4 + w;
    if (d >= N_NODES) return;
    const int l15 = lane & 15;
    const int quarter = lane >> 4;
    const int headB = (H == 2) ? (l15 >> 3) : 0;    // phase-B head (channel layout)

    int beg = ptr[d], end = ptr[d + 1];

    float ald0, ald1 = 0.f, es0, es1 = 0.f;
    if (H == 2) {
        float2 ta = *(const float2*)(aldv + (size_t)d * 2);
        float2 ts = *(const float2*)(als + (size_t)d * 2);
        ald0 = ta.x; ald1 = ta.y;
        es0 = lrelu(ts.x + ald0); es1 = lrelu(ts.y + ald1);
    } else {
        ald0 = aldv[d]; es0 = lrelu(als[d] + ald0);
    }

    // phase 0: lane-parallel logits + wave max (exact segment max incl. self)
    int k0 = beg + lane;
    int src0 = 0;
    float e0 = -INFINITY, e1 = -INFINITY;
    if (k0 < end) {
        src0 = csr[k0];
        if (H == 2) {
            float2 t = *(const float2*)(als + (size_t)src0 * 2);
            e0 = lrelu(t.x + ald0); e1 = lrelu(t.y + ald1);
        } else e0 = lrelu(als[src0] + ald0);
    }
    float m0 = fmaxf(es0, e0);
    float m1 = (H == 2) ? fmaxf(es1, e1) : 0.f;
    for (int k = k0 + 64; k < end; k += 64) {
        int s = csr[k];
        if (H == 2) {
            float2 t = *(const float2*)(als + (size_t)s * 2);
            m0 = fmaxf(m0, lrelu(t.x + ald0));
            m1 = fmaxf(m1, lrelu(t.y + ald1));
        } else m0 = fmaxf(m0, lrelu(als[s] + ald0));
    }
    #pragma unroll
    for (int off = 32; off; off >>= 1) {
        m0 = fmaxf(m0, __shfl_xor(m0, off));
        if (H == 2) m1 = fmaxf(m1, __shfl_xor(m1, off));
    }

    float l0 = 0.f, l1 = 0.f;
    float acc[8];
    #pragma unroll
    for (int i = 0; i < 8; ++i) acc[i] = 0.f;

    for (int t0 = beg; t0 < end; t0 += 64) {
        int cnt = min(64, end - t0);
        // phase A: one lane per edge -> p into LDS
        int k = t0 + lane;
        if (k < end) {
            int s; float f0, f1 = 0.f;
            if (t0 == beg) { s = src0; f0 = e0; f1 = e1; }
            else {
                s = csr[k];
                if (H == 2) {
                    float2 t = *(const float2*)(als + (size_t)s * 2);
                    f0 = lrelu(t.x + ald0); f1 = lrelu(t.y + ald1);
                } else f0 = lrelu(als[s] + ald0);
            }
            float p0 = __expf(f0 - m0);
            l0 += p0;
            s_src[w][lane] = s;
            s_p[w][0][lane] = p0;
            if (H == 2) {
                float p1 = __expf(f1 - m1);
                l1 += p1;
                s_p[w][1][lane] = p1;
            }
        }
        // phase B: 16 edges per iteration; 4 gathers in flight
        for (int j = 0; j < cnt; j += 16) {
            float pq[4]; int sq[4];
            #pragma unroll
            for (int i = 0; i < 4; ++i) {
                int e = j + 4 * i + quarter;
                int ec = min(e, cnt - 1);
                sq[i] = s_src[w][ec];
                pq[i] = (e < cnt) ? s_p[w][headB][ec] : 0.f;
            }
            uint4 u[4];
            #pragma unroll
            for (int i = 0; i < 4; ++i)
                u[i] = *(const uint4*)(Hb + (size_t)sq[i] * 128 + 8 * l15);
            #pragma unroll
            for (int i = 0; i < 4; ++i) {
                acc[0] = fmaf(pq[i], __uint_as_float(u[i].x << 16), acc[0]);
                acc[1] = fmaf(pq[i], __uint_as_float(u[i].x & 0xffff0000u), acc[1]);
                acc[2] = fmaf(pq[i], __uint_as_float(u[i].y << 16), acc[2]);
                acc[3] = fmaf(pq[i], __uint_as_float(u[i].y & 0xffff0000u), acc[3]);
                acc[4] = fmaf(pq[i], __uint_as_float(u[i].z << 16), acc[4]);
                acc[5] = fmaf(pq[i], __uint_as_float(u[i].z & 0xffff0000u), acc[5]);
                acc[6] = fmaf(pq[i], __uint_as_float(u[i].w << 16), acc[6]);
                acc[7] = fmaf(pq[i], __uint_as_float(u[i].w & 0xffff0000u), acc[7]);
            }
        }
    }

    // cross-quarter reduce
    #pragma unroll
    for (int i = 0; i < 8; ++i) {
        acc[i] += __shfl_xor(acc[i], 16);
        acc[i] += __shfl_xor(acc[i], 32);
    }
    // self-loop contribution (once, post-reduce)
    float mh  = (headB == 0) ? m0 : m1;
    float esh = (headB == 0) ? es0 : es1;
    float psh = __expf(esh - mh);
    {
        uint4 u = *(const uint4*)(Hb + (size_t)d * 128 + 8 * l15);
        acc[0] = fmaf(psh, __uint_as_float(u.x << 16), acc[0]);
        acc[1] = fmaf(psh, __uint_as_float(u.x & 0xffff0000u), acc[1]);
        acc[2] = fmaf(psh, __uint_as_float(u.y << 16), acc[2]);
        acc[3] = fmaf(psh, __uint_as_float(u.y & 0xffff0000u), acc[3]);
        acc[4] = fmaf(psh, __uint_as_float(u.z << 16), acc[4]);
        acc[5] = fmaf(psh, __uint_as_float(u.z & 0xffff0000u), acc[5]);
        acc[6] = fmaf(psh, __uint_as_float(u.w << 16), acc[6]);
        acc[7] = fmaf(psh, __uint_as_float(u.w & 0xffff0000u), acc[7]);
    }
    #pragma unroll
    for (int off = 32; off; off >>= 1) {
        l0 += __shfl_xor(l0, off);
        if (H == 2) l1 += __shfl_xor(l1, off);
    }
    float denom = ((headB == 0) ? l0 : l1) + psh;
    float inv = 1.f / (denom + 1e-16f);
    float o[8];
    float4 b4a = *(const float4*)(bias + 8 * l15);
    float4 b4b = *(const float4*)(bias + 8 * l15 + 4);
    o[0] = acc[0] * inv + b4a.x; o[1] = acc[1] * inv + b4a.y;
    o[2] = acc[2] * inv + b4a.z; o[3] = acc[3] * inv + b4a.w;
    o[4] = acc[4] * inv + b4b.x; o[5] = acc[5] * inv + b4b.y;
    o[6] = acc[6] * inv + b4b.z; o[7] = acc[7] * inv + b4b.w;
    if (DO_ELU) {
        #pragma unroll
        for (int i = 0; i < 8; ++i) o[i] = o[i] > 0.f ? o[i] : expm1f(o[i]);
    }
    if (quarter == 0) {
        if (BSPLIT) {
            ushort4 sh0, sh1, sl0, sl1;
            unsigned h;
            h = bf16rne(o[0]); sh0.x = h; sl0.x = bf16rne(o[0] - bf2f(h));
            h = bf16rne(o[1]); sh0.y = h; sl0.y = bf16rne(o[1] - bf2f(h));
            h = bf16rne(o[2]); sh0.z = h; sl0.z = bf16rne(o[2] - bf2f(h));
            h = bf16rne(o[3]); sh0.w = h; sl0.w = bf16rne(o[3] - bf2f(h));
            h = bf16rne(o[4]); sh1.x = h; sl1.x = bf16rne(o[4] - bf2f(h));
            h = bf16rne(o[5]); sh1.y = h; sl1.y = bf16rne(o[5] - bf2f(h));
            h = bf16rne(o[6]); sh1.z = h; sl1.z = bf16rne(o[6] - bf2f(h));
            h = bf16rne(o[7]); sh1.w = h; sl1.w = bf16rne(o[7] - bf2f(h));
            *(ushort4*)(oh + (size_t)d * 128 + 8 * l15)     = sh0;
            *(ushort4*)(oh + (size_t)d * 128 + 8 * l15 + 4) = sh1;
            *(ushort4*)(ol + (size_t)d * 128 + 8 * l15)     = sl0;
            *(ushort4*)(ol + (size_t)d * 128 + 8 * l15 + 4) = sl1;
        } else {
            *(float4*)(out + (size_t)d * 128 + 8 * l15)     = make_float4(o[0], o[1], o[2], o[3]);
            *(float4*)(out + (size_t)d * 128 + 8 * l15 + 4) = make_float4(o[4], o[5], o[6], o[7]);
        }
    }
}

// ---------------- launch ----------------
extern "C" void kernel_launch(void* const* d_in, const int* in_sizes, int n_in,
                              void* d_out, int out_size, void* d_ws, size_t ws_size,
                              hipStream_t stream) {
    const float* x      = (const float*)d_in[0];
    const int*   ei     = (const int*)d_in[1];
    const float* W1     = (const float*)d_in[2];
    const float* a_src1 = (const float*)d_in[3];
    const float* a_dst1 = (const float*)d_in[4];
    const float* b1     = (const float*)d_in[5];
    const float* W2     = (const float*)d_in[6];
    const float* a_src2 = (const float*)d_in[7];
    const float* a_dst2 = (const float*)d_in[8];
    const float* b2     = (const float*)d_in[9];
    float* out = (float*)d_out;

    char* ws = (char*)d_ws;
    size_t off = 0;
    auto alloc = [&](size_t bytes) { void* p = ws + off; off += (bytes + 255) & ~(size_t)255; return p; };
    int*   ptr    = (int*)alloc((N_NODES + 1) * sizeof(int));
    int*   gbcnt  = (int*)alloc(NBUCK * sizeof(int));
    int*   bbase  = (int*)alloc((NBUCK + 1) * sizeof(int));
    int*   bcur   = (int*)alloc(NBUCK * sizeof(int));
    int2*  bpairs = (int2*)alloc((size_t)N_EDGES * sizeof(int2));
    int*   csr    = (int*)alloc(N_EDGES * sizeof(int));
    unsigned short* xbh = (unsigned short*)alloc((size_t)NPAD * 128 * 2);
    unsigned short* xbl = (unsigned short*)alloc((size_t)NPAD * 128 * 2);
    unsigned short* x2h = (unsigned short*)alloc((size_t)NPAD * 128 * 2);
    unsigned short* x2l = (unsigned short*)alloc((size_t)NPAD * 128 * 2);
    unsigned short* hb  = (unsigned short*)alloc((size_t)N_NODES * 128 * 2);
    unsigned short* w1h = (unsigned short*)alloc(128 * 128 * 2);
    unsigned short* w1l = (unsigned short*)alloc(128 * 128 * 2);
    unsigned short* w2h = (unsigned short*)alloc(128 * 128 * 2);
    unsigned short* w2l = (unsigned short*)alloc(128 * 128 * 2);
    float* als    = (float*)alloc(N_NODES * 2 * sizeof(float));
    float* ald    = (float*)alloc(N_NODES * 2 * sizeof(float));

    // ---- CSR build (bucket sort; same graph both layers) ----
    zerobuf_kernel<<<1, 256, 0, stream>>>(gbcnt);
    bucketcount_kernel<<<256, 256, 0, stream>>>(ei, gbcnt);
    bucketscan_kernel<<<1, 256, 0, stream>>>(gbcnt, bbase, bcur);
    bucketscatter_kernel<<<(N_EDGES + CCHUNK - 1) / CCHUNK, 256, 0, stream>>>(ei, bcur, bpairs);
    csrfinalize_kernel<<<NBUCK, 256, 0, stream>>>(bpairs, bbase, ptr, csr);

    // ---- prep: bf16 splits ----
    convx_kernel<<<(NPAD * 128 / 4 + 255) / 256, 256, 0, stream>>>(x, xbh, xbl, x2h, x2l);
    convw_kernel<<<64, 256, 0, stream>>>(W1, w1h, w1l);
    convw_kernel<<<64, 256, 0, stream>>>(W2, w2h, w2l);

    int gblocks = NPAD / 128;             // 391
    int wblocks = (N_NODES + 3) / 4;

    // ---- layer 1 ----
    gemm_mfma_kernel<2><<<gblocks, 256, 0, stream>>>(xbh, xbl, w1h, w1l, a_src1, a_dst1, hb, als, ald, N_NODES);
    aggregate_kernel<2, 1, 1><<<wblocks, 256, 0, stream>>>(hb, als, ald, ptr, csr, b1, nullptr, x2h, x2l);

    // ---- layer 2 ----
    gemm_mfma_kernel<1><<<gblocks, 256, 0, stream>>>(x2h, x2l, w2h, w2l, a_src2, a_dst2, hb, als, ald, N_NODES);
    aggregate_kernel<1, 0, 0><<<wblocks, 256, 0, stream>>>(hb, als, ald, ptr, csr, b2, out, nullptr, nullptr);
}

// Round 14
// 174.569 us; speedup vs baseline: 1.1149x; 1.1149x over previous
//
#include <hip/hip_runtime.h>
#include <hip/hip_bf16.h>
#include <math.h>

#define N_NODES 50000
#define NPAD 50048                      // 391 * 128
#define N_EDGES 800000
#define NEG_SLOPE 0.2f
#define NBUCK ((N_NODES + 255) / 256)   // 196 buckets of 256 dsts
#define CCHUNK 4096
#define DCAP 8192

__device__ inline float lrelu(float x) { return fmaxf(x, NEG_SLOPE * x); }

__device__ inline unsigned bf16rne(float f) {
    unsigned u = __float_as_uint(f);
    return (u + 0x7fffu + ((u >> 16) & 1u)) >> 16;
}
__device__ inline float bf2f(unsigned h) { return __uint_as_float(h << 16); }

// ---------------- CSR build: LDS-staged bucket sort (packed edges) ----------------
__global__ void zerobuf_kernel(int* __restrict__ p) {
    int i = threadIdx.x;
    if (i < NBUCK) p[i] = 0;
}

__global__ __launch_bounds__(256) void bucketcount_kernel(const int* __restrict__ ei,
                                                          int* __restrict__ gbcnt) {
    __shared__ int lc[NBUCK];
    for (int i = threadIdx.x; i < NBUCK; i += 256) lc[i] = 0;
    __syncthreads();
    int stride = gridDim.x * 256;
    for (int e = blockIdx.x * 256 + threadIdx.x; e < N_EDGES; e += stride)
        atomicAdd(&lc[ei[N_EDGES + e] >> 8], 1);
    __syncthreads();
    for (int i = threadIdx.x; i < NBUCK; i += 256)
        if (lc[i]) atomicAdd(&gbcnt[i], lc[i]);
}

__global__ __launch_bounds__(256) void bucketscan_kernel(const int* __restrict__ gbcnt,
                                                         int* __restrict__ bbase,
                                                         int* __restrict__ bcur) {
    __shared__ int ss[256];
    int t = threadIdx.x;
    int v = (t < NBUCK) ? gbcnt[t] : 0;
    ss[t] = v;
    __syncthreads();
    for (int d = 1; d < 256; d <<= 1) {
        int u = (t >= d) ? ss[t - d] : 0;
        __syncthreads();
        ss[t] += u;
        __syncthreads();
    }
    int excl = ss[t] - v;
    if (t < NBUCK) { bbase[t] = excl; bcur[t] = excl; }
    if (t == 0) bbase[NBUCK] = N_EDGES;
}

// pk = src | (dst<<16); bucket = pk>>24, dst_low = (pk>>16)&255, src = pk&0xFFFF
__global__ __launch_bounds__(256) void bucketscatter_kernel(const int* __restrict__ ei,
                                                            int* __restrict__ bcur,
                                                            unsigned* __restrict__ bpairs) {
    __shared__ int cnt[NBUCK], startl[NBUCK], baseg[NBUCK], cur2[NBUCK];
    __shared__ int ss[256];
    __shared__ unsigned stage[CCHUNK];
    int t = threadIdx.x;
    int e0 = blockIdx.x * CCHUNK;
    int nume = min(CCHUNK, N_EDGES - e0);
    for (int i = t; i < NBUCK; i += 256) { cnt[i] = 0; cur2[i] = 0; }
    __syncthreads();
    int src[CCHUNK / 256], dst[CCHUNK / 256];
    #pragma unroll
    for (int j = 0; j < CCHUNK / 256; ++j) {
        int idx = t + j * 256;
        if (idx < nume) {
            src[j] = ei[e0 + idx];
            dst[j] = ei[N_EDGES + e0 + idx];
            atomicAdd(&cnt[dst[j] >> 8], 1);
        } else dst[j] = -1;
    }
    __syncthreads();
    {
        int v = (t < NBUCK) ? cnt[t] : 0;
        ss[t] = v;
        __syncthreads();
        for (int d = 1; d < 256; d <<= 1) {
            int u = (t >= d) ? ss[t - d] : 0;
            __syncthreads();
            ss[t] += u;
            __syncthreads();
        }
        if (t < NBUCK) startl[t] = ss[t] - v;
    }
    __syncthreads();
    if (t < NBUCK && cnt[t] > 0) baseg[t] = atomicAdd(&bcur[t], cnt[t]);
    __syncthreads();
    #pragma unroll
    for (int j = 0; j < CCHUNK / 256; ++j) {
        if (dst[j] >= 0) {
            int b = dst[j] >> 8;
            int slot = startl[b] + atomicAdd(&cur2[b], 1);
            stage[slot] = (unsigned)src[j] | ((unsigned)dst[j] << 16);
        }
    }
    __syncthreads();
    for (int i = t; i < nume; i += 256) {
        unsigned pk = stage[i];
        int b = pk >> 24;
        bpairs[baseg[b] + (i - startl[b])] = pk;
    }
}

__global__ __launch_bounds__(256) void csrfinalize_kernel(const unsigned* __restrict__ bpairs,
                                                          const int* __restrict__ bbase,
                                                          int* __restrict__ ptr,
                                                          unsigned short* __restrict__ csr) {
    __shared__ int cnt[256], excl[256], cur[256];
    __shared__ int ss[256];
    __shared__ unsigned P[DCAP];
    int b = blockIdx.x, t = threadIdx.x;
    int bb = bbase[b], be = bbase[b + 1];
    int n = be - bb;
    int d0 = b << 8;
    int dmax = min(256, N_NODES - d0);
    bool fits = (n <= DCAP);
    cnt[t] = 0; cur[t] = 0;
    __syncthreads();
    for (int i = t; i < n; i += 256) {
        unsigned pk = bpairs[bb + i];
        if (fits) P[i] = pk;
        atomicAdd(&cnt[(pk >> 16) & 255], 1);
    }
    __syncthreads();
    {
        int v = cnt[t];
        ss[t] = v;
        __syncthreads();
        for (int d = 1; d < 256; d <<= 1) {
            int u = (t >= d) ? ss[t - d] : 0;
            __syncthreads();
            ss[t] += u;
            __syncthreads();
        }
        excl[t] = ss[t] - v;
    }
    __syncthreads();
    if (t < dmax) ptr[d0 + t] = bb + excl[t];
    if (b == NBUCK - 1 && t == 0) ptr[N_NODES] = N_EDGES;
    for (int i = t; i < n; i += 256) {
        unsigned pk = fits ? P[i] : bpairs[bb + i];
        int ld = (pk >> 16) & 255;
        int pos = bb + excl[ld] + atomicAdd(&cur[ld], 1);
        csr[pos] = (unsigned short)(pk & 0xFFFFu);
    }
}

// ---------------- prep: W transpose + bf16 split (tiny) ----------------
__global__ __launch_bounds__(256) void convw_kernel(const float* __restrict__ W,
                                                    unsigned short* __restrict__ wth,
                                                    unsigned short* __restrict__ wtl) {
    int idx = blockIdx.x * 256 + threadIdx.x;
    if (idx >= 128 * 128) return;
    int c = idx >> 7, k = idx & 127;
    float v = W[(size_t)k * 128 + c];
    unsigned h = bf16rne(v);
    wth[idx] = (unsigned short)h;
    wtl[idx] = (unsigned short)bf16rne(v - bf2f(h));
}

// ---- MFMA GEMM (bf16x2 split, ~f32 accurate) + attention-logit epilogue ----
// AF32=1: A read from f32 and split in-register (layer 1). Else bf16 h/l arrays.
template <int H, int AF32>
__global__ __launch_bounds__(256) void gemm_mfma_kernel(const unsigned short* __restrict__ Ah,
                                                        const unsigned short* __restrict__ Al,
                                                        const float* __restrict__ Af,
                                                        const unsigned short* __restrict__ Bh,
                                                        const unsigned short* __restrict__ Bl,
                                                        const float* __restrict__ asrc,
                                                        const float* __restrict__ adst,
                                                        unsigned short* __restrict__ Hb,
                                                        float* __restrict__ als,
                                                        float* __restrict__ ald,
                                                        int nrows) {
    using bf16x8 = __attribute__((ext_vector_type(8))) short;
    using f32x4  = __attribute__((ext_vector_type(4))) float;
    const int lane = threadIdx.x & 63;
    const int wv = threadIdx.x >> 6;
    const int l15 = lane & 15;
    const int g = lane >> 4;
    const int lk = g * 8;
    const int rowbase = blockIdx.x * 128 + wv * 32;
    const int r0c = min(rowbase + l15, nrows - 1);        // clamped load rows (AF32)
    const int r1c = min(rowbase + 16 + l15, nrows - 1);

    f32x4 acc[2][8];
    #pragma unroll
    for (int rt = 0; rt < 2; ++rt)
        #pragma unroll
        for (int ct = 0; ct < 8; ++ct) acc[rt][ct] = (f32x4){0.f, 0.f, 0.f, 0.f};

    #pragma unroll
    for (int kc = 0; kc < 4; ++kc) {
        const int ko = kc * 32 + lk;
        bf16x8 ah0, ah1, al0, al1;
        if constexpr (AF32) {
            const float* b0 = Af + (size_t)r0c * 128 + ko;
            const float* b1 = Af + (size_t)r1c * 128 + ko;
            float4 u0 = *(const float4*)b0, u1 = *(const float4*)(b0 + 4);
            float4 v0 = *(const float4*)b1, v1 = *(const float4*)(b1 + 4);
            float a0[8] = {u0.x, u0.y, u0.z, u0.w, u1.x, u1.y, u1.z, u1.w};
            float a1[8] = {v0.x, v0.y, v0.z, v0.w, v1.x, v1.y, v1.z, v1.w};
            #pragma unroll
            for (int i = 0; i < 8; ++i) {
                unsigned h0 = bf16rne(a0[i]);
                ah0[i] = (short)h0; al0[i] = (short)bf16rne(a0[i] - bf2f(h0));
                unsigned h1 = bf16rne(a1[i]);
                ah1[i] = (short)h1; al1[i] = (short)bf16rne(a1[i] - bf2f(h1));
            }
        } else {
            ah0 = *(const bf16x8*)(Ah + (size_t)(rowbase + l15) * 128 + ko);
            ah1 = *(const bf16x8*)(Ah + (size_t)(rowbase + 16 + l15) * 128 + ko);
            al0 = *(const bf16x8*)(Al + (size_t)(rowbase + l15) * 128 + ko);
            al1 = *(const bf16x8*)(Al + (size_t)(rowbase + 16 + l15) * 128 + ko);
        }
        #pragma unroll
        for (int ct = 0; ct < 8; ++ct) {
            bf16x8 bh = *(const bf16x8*)(Bh + (size_t)(ct * 16 + l15) * 128 + ko);
            bf16x8 bl = *(const bf16x8*)(Bl + (size_t)(ct * 16 + l15) * 128 + ko);
            acc[0][ct] = __builtin_amdgcn_mfma_f32_16x16x32_bf16(ah0, bh, acc[0][ct], 0, 0, 0);
            acc[0][ct] = __builtin_amdgcn_mfma_f32_16x16x32_bf16(ah0, bl, acc[0][ct], 0, 0, 0);
            acc[0][ct] = __builtin_amdgcn_mfma_f32_16x16x32_bf16(al0, bh, acc[0][ct], 0, 0, 0);
            acc[1][ct] = __builtin_amdgcn_mfma_f32_16x16x32_bf16(ah1, bh, acc[1][ct], 0, 0, 0);
            acc[1][ct] = __builtin_amdgcn_mfma_f32_16x16x32_bf16(ah1, bl, acc[1][ct], 0, 0, 0);
            acc[1][ct] = __builtin_amdgcn_mfma_f32_16x16x32_bf16(al1, bh, acc[1][ct], 0, 0, 0);
        }
    }

    float as8[8], ad8[8];
    #pragma unroll
    for (int ct = 0; ct < 8; ++ct) { as8[ct] = asrc[ct * 16 + l15]; ad8[ct] = adst[ct * 16 + l15]; }

    #pragma unroll
    for (int rt = 0; rt < 2; ++rt) {
        #pragma unroll
        for (int ct = 0; ct < 8; ++ct) {
            #pragma unroll
            for (int j = 0; j < 4; ++j) {
                int row = rowbase + rt * 16 + g * 4 + j;
                if (row < nrows)
                    Hb[(size_t)row * 128 + ct * 16 + l15] = (unsigned short)bf16rne(acc[rt][ct][j]);
            }
        }
        #pragma unroll
        for (int j = 0; j < 4; ++j) {
            int row = rowbase + rt * 16 + g * 4 + j;
            if (H == 2) {
                float sp0 = 0.f, sp1 = 0.f, dp0 = 0.f, dp1 = 0.f;
                #pragma unroll
                for (int ct = 0; ct < 4; ++ct) { sp0 += acc[rt][ct][j] * as8[ct]; dp0 += acc[rt][ct][j] * ad8[ct]; }
                #pragma unroll
                for (int ct = 4; ct < 8; ++ct) { sp1 += acc[rt][ct][j] * as8[ct]; dp1 += acc[rt][ct][j] * ad8[ct]; }
                #pragma unroll
                for (int off = 1; off < 16; off <<= 1) {
                    sp0 += __shfl_xor(sp0, off); sp1 += __shfl_xor(sp1, off);
                    dp0 += __shfl_xor(dp0, off); dp1 += __shfl_xor(dp1, off);
                }
                if (l15 == 0 && row < nrows) {
                    als[(size_t)row * 2]     = sp0; als[(size_t)row * 2 + 1] = sp1;
                    ald[(size_t)row * 2]     = dp0; ald[(size_t)row * 2 + 1] = dp1;
                }
            } else {
                float sp = 0.f, dp = 0.f;
                #pragma unroll
                for (int ct = 0; ct < 8; ++ct) { sp += acc[rt][ct][j] * as8[ct]; dp += acc[rt][ct][j] * ad8[ct]; }
                #pragma unroll
                for (int off = 1; off < 16; off <<= 1) {
                    sp += __shfl_xor(sp, off); dp += __shfl_xor(dp, off);
                }
                if (l15 == 0 && row < nrows) { als[row] = sp; ald[row] = dp; }
            }
        }
    }
}

// ---- fused softmax+gather (v2, best measured): lane-parallel softmax,
// LDS-broadcast gather, 4 independent load/acc chains. ushort csr. ----
template <int H, int DO_ELU, int BSPLIT>
__global__ __launch_bounds__(256) void aggregate_kernel(const unsigned short* __restrict__ Hb,
                                                        const float* __restrict__ als,
                                                        const float* __restrict__ aldv,
                                                        const int* __restrict__ ptr,
                                                        const unsigned short* __restrict__ csr,
                                                        const float* __restrict__ bias,
                                                        float* __restrict__ out,
                                                        unsigned short* __restrict__ oh,
                                                        unsigned short* __restrict__ ol) {
    __shared__ int   s_src[4][64];
    __shared__ float s_p[4][H][64];
    const int w = threadIdx.x >> 6;
    const int lane = threadIdx.x & 63;
    const int d = blockIdx.x * 4 + w;
    if (d >= N_NODES) return;
    const int head = (H == 2) ? (lane >> 5) : 0;

    int beg = ptr[d], end = ptr[d + 1];

    float ald0, ald1 = 0.f, es0, es1 = 0.f;
    if (H == 2) {
        float2 ta = *(const float2*)(aldv + (size_t)d * 2);
        float2 ts = *(const float2*)(als + (size_t)d * 2);
        ald0 = ta.x; ald1 = ta.y;
        es0 = lrelu(ts.x + ald0); es1 = lrelu(ts.y + ald1);
    } else {
        ald0 = aldv[d]; es0 = lrelu(als[d] + ald0);
    }

    int k0 = beg + lane;
    int src0 = 0;
    float e0 = -INFINITY, e1 = -INFINITY;
    if (k0 < end) {
        src0 = csr[k0];
        if (H == 2) {
            float2 t = *(const float2*)(als + (size_t)src0 * 2);
            e0 = lrelu(t.x + ald0); e1 = lrelu(t.y + ald1);
        } else e0 = lrelu(als[src0] + ald0);
    }
    float m0 = fmaxf(es0, e0);
    float m1 = (H == 2) ? fmaxf(es1, e1) : 0.f;
    for (int k = k0 + 64; k < end; k += 64) {
        int s = csr[k];
        if (H == 2) {
            float2 t = *(const float2*)(als + (size_t)s * 2);
            m0 = fmaxf(m0, lrelu(t.x + ald0));
            m1 = fmaxf(m1, lrelu(t.y + ald1));
        } else m0 = fmaxf(m0, lrelu(als[s] + ald0));
    }
    #pragma unroll
    for (int off = 32; off; off >>= 1) {
        m0 = fmaxf(m0, __shfl_xor(m0, off));
        if (H == 2) m1 = fmaxf(m1, __shfl_xor(m1, off));
    }

    float l0 = 0.f, l1 = 0.f;
    float ax0 = 0.f, ay0 = 0.f, ax1 = 0.f, ay1 = 0.f;
    float ax2 = 0.f, ay2 = 0.f, ax3 = 0.f, ay3 = 0.f;

    for (int t0 = beg; t0 < end; t0 += 64) {
        int cnt = min(64, end - t0);
        int k = t0 + lane;
        if (k < end) {
            int s; float f0, f1 = 0.f;
            if (t0 == beg) { s = src0; f0 = e0; f1 = e1; }
            else {
                s = csr[k];
                if (H == 2) {
                    float2 t = *(const float2*)(als + (size_t)s * 2);
                    f0 = lrelu(t.x + ald0); f1 = lrelu(t.y + ald1);
                } else f0 = lrelu(als[s] + ald0);
            }
            float p0 = __expf(f0 - m0);
            l0 += p0;
            s_src[w][lane] = s;
            s_p[w][0][lane] = p0;
            if (H == 2) {
                float p1 = __expf(f1 - m1);
                l1 += p1;
                s_p[w][1][lane] = p1;
            }
        }
        int j = 0;
        for (; j + 3 < cnt; j += 4) {
            int sA = s_src[w][j],     sB = s_src[w][j + 1];
            int sC = s_src[w][j + 2], sD = s_src[w][j + 3];
            float pA = s_p[w][head][j],     pB = s_p[w][head][j + 1];
            float pC = s_p[w][head][j + 2], pD = s_p[w][head][j + 3];
            unsigned uA = ((const unsigned*)(Hb + (size_t)sA * 128))[lane];
            unsigned uB = ((const unsigned*)(Hb + (size_t)sB * 128))[lane];
            unsigned uC = ((const unsigned*)(Hb + (size_t)sC * 128))[lane];
            unsigned uD = ((const unsigned*)(Hb + (size_t)sD * 128))[lane];
            ax0 = fmaf(pA, __uint_as_float(uA << 16), ax0);
            ay0 = fmaf(pA, __uint_as_float(uA & 0xffff0000u), ay0);
            ax1 = fmaf(pB, __uint_as_float(uB << 16), ax1);
            ay1 = fmaf(pB, __uint_as_float(uB & 0xffff0000u), ay1);
            ax2 = fmaf(pC, __uint_as_float(uC << 16), ax2);
            ay2 = fmaf(pC, __uint_as_float(uC & 0xffff0000u), ay2);
            ax3 = fmaf(pD, __uint_as_float(uD << 16), ax3);
            ay3 = fmaf(pD, __uint_as_float(uD & 0xffff0000u), ay3);
        }
        for (; j < cnt; ++j) {
            int sA = s_src[w][j];
            float pA = s_p[w][head][j];
            unsigned uA = ((const unsigned*)(Hb + (size_t)sA * 128))[lane];
            ax0 = fmaf(pA, __uint_as_float(uA << 16), ax0);
            ay0 = fmaf(pA, __uint_as_float(uA & 0xffff0000u), ay0);
        }
    }

    float ax = (ax0 + ax1) + (ax2 + ax3);
    float ay = (ay0 + ay1) + (ay2 + ay3);
    float mh  = (head == 0) ? m0 : m1;
    float esh = (head == 0) ? es0 : es1;
    float psh = __expf(esh - mh);
    {
        unsigned u = ((const unsigned*)(Hb + (size_t)d * 128))[lane];
        ax = fmaf(psh, __uint_as_float(u << 16), ax);
        ay = fmaf(psh, __uint_as_float(u & 0xffff0000u), ay);
    }
    #pragma unroll
    for (int off = 32; off; off >>= 1) {
        l0 += __shfl_xor(l0, off);
        if (H == 2) l1 += __shfl_xor(l1, off);
    }
    float denom = ((head == 0) ? l0 : l1) + psh;
    float inv = 1.f / (denom + 1e-16f);
    float o0 = ax * inv + bias[2 * lane];
    float o1 = ay * inv + bias[2 * lane + 1];
    if (DO_ELU) {
        o0 = o0 > 0.f ? o0 : __expf(o0) - 1.f;
        o1 = o1 > 0.f ? o1 : __expf(o1) - 1.f;
    }
    if (BSPLIT) {
        unsigned h0 = bf16rne(o0), h1 = bf16rne(o1);
        ushort2 sh; sh.x = h0; sh.y = h1;
        ushort2 sl; sl.x = bf16rne(o0 - bf2f(h0)); sl.y = bf16rne(o1 - bf2f(h1));
        *(ushort2*)(oh + (size_t)d * 128 + 2 * lane) = sh;
        *(ushort2*)(ol + (size_t)d * 128 + 2 * lane) = sl;
    } else {
        ((float2*)(out + (size_t)d * 128))[lane] = make_float2(o0, o1);
    }
}

// ---------------- launch ----------------
extern "C" void kernel_launch(void* const* d_in, const int* in_sizes, int n_in,
                              void* d_out, int out_size, void* d_ws, size_t ws_size,
                              hipStream_t stream) {
    const float* x      = (const float*)d_in[0];
    const int*   ei     = (const int*)d_in[1];
    const float* W1     = (const float*)d_in[2];
    const float* a_src1 = (const float*)d_in[3];
    const float* a_dst1 = (const float*)d_in[4];
    const float* b1     = (const float*)d_in[5];
    const float* W2     = (const float*)d_in[6];
    const float* a_src2 = (const float*)d_in[7];
    const float* a_dst2 = (const float*)d_in[8];
    const float* b2     = (const float*)d_in[9];
    float* out = (float*)d_out;

    char* ws = (char*)d_ws;
    size_t off = 0;
    auto alloc = [&](size_t bytes) { void* p = ws + off; off += (bytes + 255) & ~(size_t)255; return p; };
    int*      ptr    = (int*)alloc((N_NODES + 1) * sizeof(int));
    int*      gbcnt  = (int*)alloc(NBUCK * sizeof(int));
    int*      bbase  = (int*)alloc((NBUCK + 1) * sizeof(int));
    int*      bcur   = (int*)alloc(NBUCK * sizeof(int));
    unsigned* bpairs = (unsigned*)alloc((size_t)N_EDGES * sizeof(unsigned));
    unsigned short* csr = (unsigned short*)alloc((size_t)N_EDGES * sizeof(unsigned short));
    unsigned short* x2h = (unsigned short*)alloc((size_t)NPAD * 128 * 2);
    unsigned short* x2l = (unsigned short*)alloc((size_t)NPAD * 128 * 2);
    unsigned short* hb  = (unsigned short*)alloc((size_t)N_NODES * 128 * 2);
    unsigned short* w1h = (unsigned short*)alloc(128 * 128 * 2);
    unsigned short* w1l = (unsigned short*)alloc(128 * 128 * 2);
    unsigned short* w2h = (unsigned short*)alloc(128 * 128 * 2);
    unsigned short* w2l = (unsigned short*)alloc(128 * 128 * 2);
    float* als    = (float*)alloc(N_NODES * 2 * sizeof(float));
    float* ald    = (float*)alloc(N_NODES * 2 * sizeof(float));

    // ---- CSR build (packed bucket sort; same graph both layers) ----
    zerobuf_kernel<<<1, 256, 0, stream>>>(gbcnt);
    bucketcount_kernel<<<256, 256, 0, stream>>>(ei, gbcnt);
    bucketscan_kernel<<<1, 256, 0, stream>>>(gbcnt, bbase, bcur);
    bucketscatter_kernel<<<(N_EDGES + CCHUNK - 1) / CCHUNK, 256, 0, stream>>>(ei, bcur, bpairs);
    csrfinalize_kernel<<<NBUCK, 256, 0, stream>>>(bpairs, bbase, ptr, csr);

    // ---- prep: W bf16 splits (x is split in-register in gemm layer 1) ----
    convw_kernel<<<64, 256, 0, stream>>>(W1, w1h, w1l);
    convw_kernel<<<64, 256, 0, stream>>>(W2, w2h, w2l);

    int gblocks = NPAD / 128;             // 391
    int wblocks = (N_NODES + 3) / 4;

    // ---- layer 1 ----
    gemm_mfma_kernel<2, 1><<<gblocks, 256, 0, stream>>>(nullptr, nullptr, x, w1h, w1l,
                                                        a_src1, a_dst1, hb, als, ald, N_NODES);
    aggregate_kernel<2, 1, 1><<<wblocks, 256, 0, stream>>>(hb, als, ald, ptr, csr, b1,
                                                           nullptr, x2h, x2l);

    // ---- layer 2 ----
    gemm_mfma_kernel<1, 0><<<gblocks, 256, 0, stream>>>(x2h, x2l, nullptr, w2h, w2l,
                                                        a_src2, a_dst2, hb, als, ald, N_NODES);
    aggregate_kernel<1, 0, 0><<<wblocks, 256, 0, stream>>>(hb, als, ald, ptr, csr, b2,
                                                           out, nullptr, nullptr);
}

// Round 16
// 170.811 us; speedup vs baseline: 1.1394x; 1.0220x over previous
//
#include <hip/hip_runtime.h>
#include <hip/hip_bf16.h>
#include <math.h>

#define N_NODES 50000
#define NPAD 50048                      // 391 * 128
#define N_EDGES 800000
#define NEG_SLOPE 0.2f
#define NBUCK ((N_NODES + 255) / 256)   // 196 buckets of 256 dsts
#define CCHUNK 4096
#define DCAP 8192

__device__ inline float lrelu(float x) { return fmaxf(x, NEG_SLOPE * x); }

__device__ inline unsigned bf16rne(float f) {
    unsigned u = __float_as_uint(f);
    return (u + 0x7fffu + ((u >> 16) & 1u)) >> 16;
}
__device__ inline float bf2f(unsigned h) { return __uint_as_float(h << 16); }

// ---------------- CSR build: LDS-staged bucket sort (packed edges) ----------------
__global__ void zerobuf_kernel(int* __restrict__ p) {
    int i = threadIdx.x;
    if (i < NBUCK) p[i] = 0;
}

__global__ __launch_bounds__(256) void bucketcount_kernel(const int* __restrict__ ei,
                                                          int* __restrict__ gbcnt) {
    __shared__ int lc[NBUCK];
    for (int i = threadIdx.x; i < NBUCK; i += 256) lc[i] = 0;
    __syncthreads();
    int stride = gridDim.x * 256;
    for (int e = blockIdx.x * 256 + threadIdx.x; e < N_EDGES; e += stride)
        atomicAdd(&lc[ei[N_EDGES + e] >> 8], 1);
    __syncthreads();
    for (int i = threadIdx.x; i < NBUCK; i += 256)
        if (lc[i]) atomicAdd(&gbcnt[i], lc[i]);
}

// block 0: scan bucket counts; blocks 1..128: W1/W2 transpose+bf16 split
__global__ __launch_bounds__(256) void scan_convw_kernel(const int* __restrict__ gbcnt,
                                                         int* __restrict__ bbase,
                                                         int* __restrict__ bcur,
                                                         const float* __restrict__ W1,
                                                         unsigned short* __restrict__ w1h,
                                                         unsigned short* __restrict__ w1l,
                                                         const float* __restrict__ W2,
                                                         unsigned short* __restrict__ w2h,
                                                         unsigned short* __restrict__ w2l) {
    int b = blockIdx.x;
    int t = threadIdx.x;
    if (b == 0) {
        __shared__ int ss[256];
        int v = (t < NBUCK) ? gbcnt[t] : 0;
        ss[t] = v;
        __syncthreads();
        for (int d = 1; d < 256; d <<= 1) {
            int u = (t >= d) ? ss[t - d] : 0;
            __syncthreads();
            ss[t] += u;
            __syncthreads();
        }
        int excl = ss[t] - v;
        if (t < NBUCK) { bbase[t] = excl; bcur[t] = excl; }
        if (t == 0) bbase[NBUCK] = N_EDGES;
    } else {
        int idx = (b - 1) * 256 + t;          // 0..32767 over both weight matrices
        const float* W = W1;
        unsigned short* th = w1h;
        unsigned short* tl = w1l;
        if (idx >= 128 * 128) { W = W2; th = w2h; tl = w2l; idx -= 128 * 128; }
        int c = idx >> 7, k = idx & 127;
        float v = W[(size_t)k * 128 + c];
        unsigned h = bf16rne(v);
        th[idx] = (unsigned short)h;
        tl[idx] = (unsigned short)bf16rne(v - bf2f(h));
    }
}

// pk = src | (dst<<16); bucket = pk>>24, dst_low = (pk>>16)&255, src = pk&0xFFFF
__global__ __launch_bounds__(256) void bucketscatter_kernel(const int* __restrict__ ei,
                                                            int* __restrict__ bcur,
                                                            unsigned* __restrict__ bpairs) {
    __shared__ int cnt[NBUCK], startl[NBUCK], baseg[NBUCK], cur2[NBUCK];
    __shared__ int ss[256];
    __shared__ unsigned stage[CCHUNK];
    int t = threadIdx.x;
    int e0 = blockIdx.x * CCHUNK;
    int nume = min(CCHUNK, N_EDGES - e0);
    for (int i = t; i < NBUCK; i += 256) { cnt[i] = 0; cur2[i] = 0; }
    __syncthreads();
    int src[CCHUNK / 256], dst[CCHUNK / 256];
    #pragma unroll
    for (int j = 0; j < CCHUNK / 256; ++j) {
        int idx = t + j * 256;
        if (idx < nume) {
            src[j] = ei[e0 + idx];
            dst[j] = ei[N_EDGES + e0 + idx];
            atomicAdd(&cnt[dst[j] >> 8], 1);
        } else dst[j] = -1;
    }
    __syncthreads();
    {
        int v = (t < NBUCK) ? cnt[t] : 0;
        ss[t] = v;
        __syncthreads();
        for (int d = 1; d < 256; d <<= 1) {
            int u = (t >= d) ? ss[t - d] : 0;
            __syncthreads();
            ss[t] += u;
            __syncthreads();
        }
        if (t < NBUCK) startl[t] = ss[t] - v;
    }
    __syncthreads();
    if (t < NBUCK && cnt[t] > 0) baseg[t] = atomicAdd(&bcur[t], cnt[t]);
    __syncthreads();
    #pragma unroll
    for (int j = 0; j < CCHUNK / 256; ++j) {
        if (dst[j] >= 0) {
            int b = dst[j] >> 8;
            int slot = startl[b] + atomicAdd(&cur2[b], 1);
            stage[slot] = (unsigned)src[j] | ((unsigned)dst[j] << 16);
        }
    }
    __syncthreads();
    for (int i = t; i < nume; i += 256) {
        unsigned pk = stage[i];
        int b = pk >> 24;
        bpairs[baseg[b] + (i - startl[b])] = pk;
    }
}

__global__ __launch_bounds__(256) void csrfinalize_kernel(const unsigned* __restrict__ bpairs,
                                                          const int* __restrict__ bbase,
                                                          int* __restrict__ ptr,
                                                          unsigned short* __restrict__ csr) {
    __shared__ int cnt[256], excl[256], cur[256];
    __shared__ int ss[256];
    __shared__ unsigned P[DCAP];
    int b = blockIdx.x, t = threadIdx.x;
    int bb = bbase[b], be = bbase[b + 1];
    int n = be - bb;
    int d0 = b << 8;
    int dmax = min(256, N_NODES - d0);
    bool fits = (n <= DCAP);
    cnt[t] = 0; cur[t] = 0;
    __syncthreads();
    for (int i = t; i < n; i += 256) {
        unsigned pk = bpairs[bb + i];
        if (fits) P[i] = pk;
        atomicAdd(&cnt[(pk >> 16) & 255], 1);
    }
    __syncthreads();
    {
        int v = cnt[t];
        ss[t] = v;
        __syncthreads();
        for (int d = 1; d < 256; d <<= 1) {
            int u = (t >= d) ? ss[t - d] : 0;
            __syncthreads();
            ss[t] += u;
            __syncthreads();
        }
        excl[t] = ss[t] - v;
    }
    __syncthreads();
    if (t < dmax) ptr[d0 + t] = bb + excl[t];
    if (b == NBUCK - 1 && t == 0) ptr[N_NODES] = N_EDGES;
    for (int i = t; i < n; i += 256) {
        unsigned pk = fits ? P[i] : bpairs[bb + i];
        int ld = (pk >> 16) & 255;
        int pos = bb + excl[ld] + atomicAdd(&cur[ld], 1);
        csr[pos] = (unsigned short)(pk & 0xFFFFu);
    }
}

// ---- MFMA GEMM (bf16x2 split, ~f32 accurate) + attention-logit epilogue ----
// AF32=1: A read from f32 and split in-register (layer 1). Else bf16 h/l arrays.
template <int H, int AF32>
__global__ __launch_bounds__(256) void gemm_mfma_kernel(const unsigned short* __restrict__ Ah,
                                                        const unsigned short* __restrict__ Al,
                                                        const float* __restrict__ Af,
                                                        const unsigned short* __restrict__ Bh,
                                                        const unsigned short* __restrict__ Bl,
                                                        const float* __restrict__ asrc,
                                                        const float* __restrict__ adst,
                                                        unsigned short* __restrict__ Hb,
                                                        float* __restrict__ als,
                                                        float* __restrict__ ald,
                                                        int nrows) {
    using bf16x8 = __attribute__((ext_vector_type(8))) short;
    using f32x4  = __attribute__((ext_vector_type(4))) float;
    const int lane = threadIdx.x & 63;
    const int wv = threadIdx.x >> 6;
    const int l15 = lane & 15;
    const int g = lane >> 4;
    const int lk = g * 8;
    const int rowbase = blockIdx.x * 128 + wv * 32;
    const int r0c = min(rowbase + l15, nrows - 1);
    const int r1c = min(rowbase + 16 + l15, nrows - 1);

    f32x4 acc[2][8];
    #pragma unroll
    for (int rt = 0; rt < 2; ++rt)
        #pragma unroll
        for (int ct = 0; ct < 8; ++ct) acc[rt][ct] = (f32x4){0.f, 0.f, 0.f, 0.f};

    #pragma unroll
    for (int kc = 0; kc < 4; ++kc) {
        const int ko = kc * 32 + lk;
        bf16x8 ah0, ah1, al0, al1;
        if constexpr (AF32) {
            const float* b0 = Af + (size_t)r0c * 128 + ko;
            const float* b1 = Af + (size_t)r1c * 128 + ko;
            float4 u0 = *(const float4*)b0, u1 = *(const float4*)(b0 + 4);
            float4 v0 = *(const float4*)b1, v1 = *(const float4*)(b1 + 4);
            float a0[8] = {u0.x, u0.y, u0.z, u0.w, u1.x, u1.y, u1.z, u1.w};
            float a1[8] = {v0.x, v0.y, v0.z, v0.w, v1.x, v1.y, v1.z, v1.w};
            #pragma unroll
            for (int i = 0; i < 8; ++i) {
                unsigned h0 = bf16rne(a0[i]);
                ah0[i] = (short)h0; al0[i] = (short)bf16rne(a0[i] - bf2f(h0));
                unsigned h1 = bf16rne(a1[i]);
                ah1[i] = (short)h1; al1[i] = (short)bf16rne(a1[i] - bf2f(h1));
            }
        } else {
            ah0 = *(const bf16x8*)(Ah + (size_t)(rowbase + l15) * 128 + ko);
            ah1 = *(const bf16x8*)(Ah + (size_t)(rowbase + 16 + l15) * 128 + ko);
            al0 = *(const bf16x8*)(Al + (size_t)(rowbase + l15) * 128 + ko);
            al1 = *(const bf16x8*)(Al + (size_t)(rowbase + 16 + l15) * 128 + ko);
        }
        #pragma unroll
        for (int ct = 0; ct < 8; ++ct) {
            bf16x8 bh = *(const bf16x8*)(Bh + (size_t)(ct * 16 + l15) * 128 + ko);
            bf16x8 bl = *(const bf16x8*)(Bl + (size_t)(ct * 16 + l15) * 128 + ko);
            acc[0][ct] = __builtin_amdgcn_mfma_f32_16x16x32_bf16(ah0, bh, acc[0][ct], 0, 0, 0);
            acc[0][ct] = __builtin_amdgcn_mfma_f32_16x16x32_bf16(ah0, bl, acc[0][ct], 0, 0, 0);
            acc[0][ct] = __builtin_amdgcn_mfma_f32_16x16x32_bf16(al0, bh, acc[0][ct], 0, 0, 0);
            acc[1][ct] = __builtin_amdgcn_mfma_f32_16x16x32_bf16(ah1, bh, acc[1][ct], 0, 0, 0);
            acc[1][ct] = __builtin_amdgcn_mfma_f32_16x16x32_bf16(ah1, bl, acc[1][ct], 0, 0, 0);
            acc[1][ct] = __builtin_amdgcn_mfma_f32_16x16x32_bf16(al1, bh, acc[1][ct], 0, 0, 0);
        }
    }

    float as8[8], ad8[8];
    #pragma unroll
    for (int ct = 0; ct < 8; ++ct) { as8[ct] = asrc[ct * 16 + l15]; ad8[ct] = adst[ct * 16 + l15]; }

    #pragma unroll
    for (int rt = 0; rt < 2; ++rt) {
        #pragma unroll
        for (int ct = 0; ct < 8; ++ct) {
            #pragma unroll
            for (int j = 0; j < 4; ++j) {
                int row = rowbase + rt * 16 + g * 4 + j;
                if (row < nrows)
                    Hb[(size_t)row * 128 + ct * 16 + l15] = (unsigned short)bf16rne(acc[rt][ct][j]);
            }
        }
        #pragma unroll
        for (int j = 0; j < 4; ++j) {
            int row = rowbase + rt * 16 + g * 4 + j;
            if (H == 2) {
                float sp0 = 0.f, sp1 = 0.f, dp0 = 0.f, dp1 = 0.f;
                #pragma unroll
                for (int ct = 0; ct < 4; ++ct) { sp0 += acc[rt][ct][j] * as8[ct]; dp0 += acc[rt][ct][j] * ad8[ct]; }
                #pragma unroll
                for (int ct = 4; ct < 8; ++ct) { sp1 += acc[rt][ct][j] * as8[ct]; dp1 += acc[rt][ct][j] * ad8[ct]; }
                #pragma unroll
                for (int off = 1; off < 16; off <<= 1) {
                    sp0 += __shfl_xor(sp0, off); sp1 += __shfl_xor(sp1, off);
                    dp0 += __shfl_xor(dp0, off); dp1 += __shfl_xor(dp1, off);
                }
                if (l15 == 0 && row < nrows) {
                    als[(size_t)row * 2]     = sp0; als[(size_t)row * 2 + 1] = sp1;
                    ald[(size_t)row * 2]     = dp0; ald[(size_t)row * 2 + 1] = dp1;
                }
            } else {
                float sp = 0.f, dp = 0.f;
                #pragma unroll
                for (int ct = 0; ct < 8; ++ct) { sp += acc[rt][ct][j] * as8[ct]; dp += acc[rt][ct][j] * ad8[ct]; }
                #pragma unroll
                for (int off = 1; off < 16; off <<= 1) {
                    sp += __shfl_xor(sp, off); dp += __shfl_xor(dp, off);
                }
                if (l15 == 0 && row < nrows) { als[row] = sp; ald[row] = dp; }
            }
        }
    }
}

// ---- fused softmax+gather (v2 + 32-bit saddr gathers; Hb row = 64 dwords) ----
template <int H, int DO_ELU, int BSPLIT>
__global__ __launch_bounds__(256) void aggregate_kernel(const unsigned short* __restrict__ Hb,
                                                        const float* __restrict__ als,
                                                        const float* __restrict__ aldv,
                                                        const int* __restrict__ ptr,
                                                        const unsigned short* __restrict__ csr,
                                                        const float* __restrict__ bias,
                                                        float* __restrict__ out,
                                                        unsigned short* __restrict__ oh,
                                                        unsigned short* __restrict__ ol) {
    __shared__ int   s_src[4][64];
    __shared__ float s_p[4][H][64];
    const unsigned* __restrict__ Hb32 = (const unsigned*)Hb;      // row stride = 64 dwords
    const float2*   __restrict__ als2 = (const float2*)als;
    const int w = threadIdx.x >> 6;
    const int lane = threadIdx.x & 63;
    const int d = blockIdx.x * 4 + w;
    if (d >= N_NODES) return;
    const int head = (H == 2) ? (lane >> 5) : 0;

    int beg = ptr[d], end = ptr[d + 1];

    float ald0, ald1 = 0.f, es0, es1 = 0.f;
    if (H == 2) {
        float2 ta = *(const float2*)(aldv + (size_t)d * 2);
        float2 ts = als2[(unsigned)d];
        ald0 = ta.x; ald1 = ta.y;
        es0 = lrelu(ts.x + ald0); es1 = lrelu(ts.y + ald1);
    } else {
        ald0 = aldv[d]; es0 = lrelu(als[d] + ald0);
    }

    int k0 = beg + lane;
    int src0 = 0;
    float e0 = -INFINITY, e1 = -INFINITY;
    if (k0 < end) {
        src0 = csr[k0];
        if (H == 2) {
            float2 t = als2[(unsigned)src0];
            e0 = lrelu(t.x + ald0); e1 = lrelu(t.y + ald1);
        } else e0 = lrelu(als[(unsigned)src0] + ald0);
    }
    float m0 = fmaxf(es0, e0);
    float m1 = (H == 2) ? fmaxf(es1, e1) : 0.f;
    for (int k = k0 + 64; k < end; k += 64) {
        int s = csr[k];
        if (H == 2) {
            float2 t = als2[(unsigned)s];
            m0 = fmaxf(m0, lrelu(t.x + ald0));
            m1 = fmaxf(m1, lrelu(t.y + ald1));
        } else m0 = fmaxf(m0, lrelu(als[(unsigned)s] + ald0));
    }
    #pragma unroll
    for (int off = 32; off; off >>= 1) {
        m0 = fmaxf(m0, __shfl_xor(m0, off));
        if (H == 2) m1 = fmaxf(m1, __shfl_xor(m1, off));
    }

    float l0 = 0.f, l1 = 0.f;
    float ax0 = 0.f, ay0 = 0.f, ax1 = 0.f, ay1 = 0.f;
    float ax2 = 0.f, ay2 = 0.f, ax3 = 0.f, ay3 = 0.f;

    for (int t0 = beg; t0 < end; t0 += 64) {
        int cnt = min(64, end - t0);
        int k = t0 + lane;
        if (k < end) {
            int s; float f0, f1 = 0.f;
            if (t0 == beg) { s = src0; f0 = e0; f1 = e1; }
            else {
                s = csr[k];
                if (H == 2) {
                    float2 t = als2[(unsigned)s];
                    f0 = lrelu(t.x + ald0); f1 = lrelu(t.y + ald1);
                } else f0 = lrelu(als[(unsigned)s] + ald0);
            }
            float p0 = __expf(f0 - m0);
            l0 += p0;
            s_src[w][lane] = s;
            s_p[w][0][lane] = p0;
            if (H == 2) {
                float p1 = __expf(f1 - m1);
                l1 += p1;
                s_p[w][1][lane] = p1;
            }
        }
        int j = 0;
        for (; j + 3 < cnt; j += 4) {
            int sA = s_src[w][j],     sB = s_src[w][j + 1];
            int sC = s_src[w][j + 2], sD = s_src[w][j + 3];
            float pA = s_p[w][head][j],     pB = s_p[w][head][j + 1];
            float pC = s_p[w][head][j + 2], pD = s_p[w][head][j + 3];
            unsigned uA = Hb32[((unsigned)sA << 6) + lane];
            unsigned uB = Hb32[((unsigned)sB << 6) + lane];
            unsigned uC = Hb32[((unsigned)sC << 6) + lane];
            unsigned uD = Hb32[((unsigned)sD << 6) + lane];
            ax0 = fmaf(pA, __uint_as_float(uA << 16), ax0);
            ay0 = fmaf(pA, __uint_as_float(uA & 0xffff0000u), ay0);
            ax1 = fmaf(pB, __uint_as_float(uB << 16), ax1);
            ay1 = fmaf(pB, __uint_as_float(uB & 0xffff0000u), ay1);
            ax2 = fmaf(pC, __uint_as_float(uC << 16), ax2);
            ay2 = fmaf(pC, __uint_as_float(uC & 0xffff0000u), ay2);
            ax3 = fmaf(pD, __uint_as_float(uD << 16), ax3);
            ay3 = fmaf(pD, __uint_as_float(uD & 0xffff0000u), ay3);
        }
        for (; j < cnt; ++j) {
            int sA = s_src[w][j];
            float pA = s_p[w][head][j];
            unsigned uA = Hb32[((unsigned)sA << 6) + lane];
            ax0 = fmaf(pA, __uint_as_float(uA << 16), ax0);
            ay0 = fmaf(pA, __uint_as_float(uA & 0xffff0000u), ay0);
        }
    }

    float ax = (ax0 + ax1) + (ax2 + ax3);
    float ay = (ay0 + ay1) + (ay2 + ay3);
    float mh  = (head == 0) ? m0 : m1;
    float esh = (head == 0) ? es0 : es1;
    float psh = __expf(esh - mh);
    {
        unsigned u = Hb32[((unsigned)d << 6) + lane];
        ax = fmaf(psh, __uint_as_float(u << 16), ax);
        ay = fmaf(psh, __uint_as_float(u & 0xffff0000u), ay);
    }
    #pragma unroll
    for (int off = 32; off; off >>= 1) {
        l0 += __shfl_xor(l0, off);
        if (H == 2) l1 += __shfl_xor(l1, off);
    }
    float denom = ((head == 0) ? l0 : l1) + psh;
    float inv = 1.f / (denom + 1e-16f);
    float o0 = ax * inv + bias[2 * lane];
    float o1 = ay * inv + bias[2 * lane + 1];
    if (DO_ELU) {
        o0 = o0 > 0.f ? o0 : __expf(o0) - 1.f;
        o1 = o1 > 0.f ? o1 : __expf(o1) - 1.f;
    }
    if (BSPLIT) {
        unsigned h0 = bf16rne(o0), h1 = bf16rne(o1);
        ushort2 sh; sh.x = h0; sh.y = h1;
        ushort2 sl; sl.x = bf16rne(o0 - bf2f(h0)); sl.y = bf16rne(o1 - bf2f(h1));
        *(ushort2*)(oh + (size_t)d * 128 + 2 * lane) = sh;
        *(ushort2*)(ol + (size_t)d * 128 + 2 * lane) = sl;
    } else {
        ((float2*)(out + (size_t)d * 128))[lane] = make_float2(o0, o1);
    }
}

// ---------------- launch ----------------
extern "C" void kernel_launch(void* const* d_in, const int* in_sizes, int n_in,
                              void* d_out, int out_size, void* d_ws, size_t ws_size,
                              hipStream_t stream) {
    const float* x      = (const float*)d_in[0];
    const int*   ei     = (const int*)d_in[1];
    const float* W1     = (const float*)d_in[2];
    const float* a_src1 = (const float*)d_in[3];
    const float* a_dst1 = (const float*)d_in[4];
    const float* b1     = (const float*)d_in[5];
    const float* W2     = (const float*)d_in[6];
    const float* a_src2 = (const float*)d_in[7];
    const float* a_dst2 = (const float*)d_in[8];
    const float* b2     = (const float*)d_in[9];
    float* out = (float*)d_out;

    char* ws = (char*)d_ws;
    size_t off = 0;
    auto alloc = [&](size_t bytes) { void* p = ws + off; off += (bytes + 255) & ~(size_t)255; return p; };
    int*      ptr    = (int*)alloc((N_NODES + 1) * sizeof(int));
    int*      gbcnt  = (int*)alloc(NBUCK * sizeof(int));
    int*      bbase  = (int*)alloc((NBUCK + 1) * sizeof(int));
    int*      bcur   = (int*)alloc(NBUCK * sizeof(int));
    unsigned* bpairs = (unsigned*)alloc((size_t)N_EDGES * sizeof(unsigned));
    unsigned short* csr = (unsigned short*)alloc((size_t)N_EDGES * sizeof(unsigned short));
    unsigned short* x2h = (unsigned short*)alloc((size_t)NPAD * 128 * 2);
    unsigned short* x2l = (unsigned short*)alloc((size_t)NPAD * 128 * 2);
    unsigned short* hb  = (unsigned short*)alloc((size_t)N_NODES * 128 * 2);
    unsigned short* w1h = (unsigned short*)alloc(128 * 128 * 2);
    unsigned short* w1l = (unsigned short*)alloc(128 * 128 * 2);
    unsigned short* w2h = (unsigned short*)alloc(128 * 128 * 2);
    unsigned short* w2l = (unsigned short*)alloc(128 * 128 * 2);
    float* als    = (float*)alloc(N_NODES * 2 * sizeof(float));
    float* ald    = (float*)alloc(N_NODES * 2 * sizeof(float));

    // ---- CSR build (packed bucket sort; same graph both layers) ----
    zerobuf_kernel<<<1, 256, 0, stream>>>(gbcnt);
    bucketcount_kernel<<<256, 256, 0, stream>>>(ei, gbcnt);
    scan_convw_kernel<<<129, 256, 0, stream>>>(gbcnt, bbase, bcur, W1, w1h, w1l, W2, w2h, w2l);
    bucketscatter_kernel<<<(N_EDGES + CCHUNK - 1) / CCHUNK, 256, 0, stream>>>(ei, bcur, bpairs);
    csrfinalize_kernel<<<NBUCK, 256, 0, stream>>>(bpairs, bbase, ptr, csr);

    int gblocks = NPAD / 128;             // 391
    int wblocks = (N_NODES + 3) / 4;

    // ---- layer 1 ----
    gemm_mfma_kernel<2, 1><<<gblocks, 256, 0, stream>>>(nullptr, nullptr, x, w1h, w1l,
                                                        a_src1, a_dst1, hb, als, ald, N_NODES);
    aggregate_kernel<2, 1, 1><<<wblocks, 256, 0, stream>>>(hb, als, ald, ptr, csr, b1,
                                                           nullptr, x2h, x2l);

    // ---- layer 2 ----
    gemm_mfma_kernel<1, 0><<<gblocks, 256, 0, stream>>>(x2h, x2l, nullptr, w2h, w2l,
                                                        a_src2, a_dst2, hb, als, ald, N_NODES);
    aggregate_kernel<1, 0, 0><<<wblocks, 256, 0, stream>>>(hb, als, ald, ptr, csr, b2,
                                                           out, nullptr, nullptr);
}

// Round 17
// 170.227 us; speedup vs baseline: 1.1433x; 1.0034x over previous
//
#include <hip/hip_runtime.h>
#include <hip/hip_bf16.h>
#include <math.h>

#define N_NODES 50000
#define NPAD 50048                      // 391 * 128
#define N_EDGES 800000
#define NEG_SLOPE 0.2f
#define NBUCK ((N_NODES + 255) / 256)   // 196 buckets of 256 dsts
#define CCHUNK 4096
#define DCAP 8192

__device__ inline float lrelu(float x) { return fmaxf(x, NEG_SLOPE * x); }

__device__ inline unsigned bf16rne(float f) {
    unsigned u = __float_as_uint(f);
    return (u + 0x7fffu + ((u >> 16) & 1u)) >> 16;
}
__device__ inline float bf2f(unsigned h) { return __uint_as_float(h << 16); }

// ---------------- CSR build: LDS-staged bucket sort (packed edges) ----------------
__global__ void zerobuf_kernel(int* __restrict__ p) {
    int i = threadIdx.x;
    if (i < NBUCK) p[i] = 0;
}

__global__ __launch_bounds__(256) void bucketcount_kernel(const int* __restrict__ ei,
                                                          int* __restrict__ gbcnt) {
    __shared__ int lc[NBUCK];
    for (int i = threadIdx.x; i < NBUCK; i += 256) lc[i] = 0;
    __syncthreads();
    int stride = gridDim.x * 256;
    for (int e = blockIdx.x * 256 + threadIdx.x; e < N_EDGES; e += stride)
        atomicAdd(&lc[ei[N_EDGES + e] >> 8], 1);
    __syncthreads();
    for (int i = threadIdx.x; i < NBUCK; i += 256)
        if (lc[i]) atomicAdd(&gbcnt[i], lc[i]);
}

// block 0: scan bucket counts; blocks 1..128: W1/W2 transpose+bf16 split
__global__ __launch_bounds__(256) void scan_convw_kernel(const int* __restrict__ gbcnt,
                                                         int* __restrict__ bbase,
                                                         int* __restrict__ bcur,
                                                         const float* __restrict__ W1,
                                                         unsigned short* __restrict__ w1h,
                                                         unsigned short* __restrict__ w1l,
                                                         const float* __restrict__ W2,
                                                         unsigned short* __restrict__ w2h,
                                                         unsigned short* __restrict__ w2l) {
    int b = blockIdx.x;
    int t = threadIdx.x;
    if (b == 0) {
        __shared__ int ss[256];
        int v = (t < NBUCK) ? gbcnt[t] : 0;
        ss[t] = v;
        __syncthreads();
        for (int d = 1; d < 256; d <<= 1) {
            int u = (t >= d) ? ss[t - d] : 0;
            __syncthreads();
            ss[t] += u;
            __syncthreads();
        }
        int excl = ss[t] - v;
        if (t < NBUCK) { bbase[t] = excl; bcur[t] = excl; }
        if (t == 0) bbase[NBUCK] = N_EDGES;
    } else {
        int idx = (b - 1) * 256 + t;
        const float* W = W1;
        unsigned short* th = w1h;
        unsigned short* tl = w1l;
        if (idx >= 128 * 128) { W = W2; th = w2h; tl = w2l; idx -= 128 * 128; }
        int c = idx >> 7, k = idx & 127;
        float v = W[(size_t)k * 128 + c];
        unsigned h = bf16rne(v);
        th[idx] = (unsigned short)h;
        tl[idx] = (unsigned short)bf16rne(v - bf2f(h));
    }
}

// pk = src | (dst<<16); bucket = pk>>24, dst_low = (pk>>16)&255, src = pk&0xFFFF
__global__ __launch_bounds__(256) void bucketscatter_kernel(const int* __restrict__ ei,
                                                            int* __restrict__ bcur,
                                                            unsigned* __restrict__ bpairs) {
    __shared__ int cnt[NBUCK], startl[NBUCK], baseg[NBUCK], cur2[NBUCK];
    __shared__ int ss[256];
    __shared__ unsigned stage[CCHUNK];
    int t = threadIdx.x;
    int e0 = blockIdx.x * CCHUNK;
    int nume = min(CCHUNK, N_EDGES - e0);
    for (int i = t; i < NBUCK; i += 256) { cnt[i] = 0; cur2[i] = 0; }
    __syncthreads();
    int src[CCHUNK / 256], dst[CCHUNK / 256];
    #pragma unroll
    for (int j = 0; j < CCHUNK / 256; ++j) {
        int idx = t + j * 256;
        if (idx < nume) {
            src[j] = ei[e0 + idx];
            dst[j] = ei[N_EDGES + e0 + idx];
            atomicAdd(&cnt[dst[j] >> 8], 1);
        } else dst[j] = -1;
    }
    __syncthreads();
    {
        int v = (t < NBUCK) ? cnt[t] : 0;
        ss[t] = v;
        __syncthreads();
        for (int d = 1; d < 256; d <<= 1) {
            int u = (t >= d) ? ss[t - d] : 0;
            __syncthreads();
            ss[t] += u;
            __syncthreads();
        }
        if (t < NBUCK) startl[t] = ss[t] - v;
    }
    __syncthreads();
    if (t < NBUCK && cnt[t] > 0) baseg[t] = atomicAdd(&bcur[t], cnt[t]);
    __syncthreads();
    #pragma unroll
    for (int j = 0; j < CCHUNK / 256; ++j) {
        if (dst[j] >= 0) {
            int b = dst[j] >> 8;
            int slot = startl[b] + atomicAdd(&cur2[b], 1);
            stage[slot] = (unsigned)src[j] | ((unsigned)dst[j] << 16);
        }
    }
    __syncthreads();
    for (int i = t; i < nume; i += 256) {
        unsigned pk = stage[i];
        int b = pk >> 24;
        bpairs[baseg[b] + (i - startl[b])] = pk;
    }
}

__global__ __launch_bounds__(256) void csrfinalize_kernel(const unsigned* __restrict__ bpairs,
                                                          const int* __restrict__ bbase,
                                                          int* __restrict__ ptr,
                                                          unsigned short* __restrict__ csr) {
    __shared__ int cnt[256], excl[256], cur[256];
    __shared__ int ss[256];
    __shared__ unsigned P[DCAP];
    int b = blockIdx.x, t = threadIdx.x;
    int bb = bbase[b], be = bbase[b + 1];
    int n = be - bb;
    int d0 = b << 8;
    int dmax = min(256, N_NODES - d0);
    bool fits = (n <= DCAP);
    cnt[t] = 0; cur[t] = 0;
    __syncthreads();
    for (int i = t; i < n; i += 256) {
        unsigned pk = bpairs[bb + i];
        if (fits) P[i] = pk;
        atomicAdd(&cnt[(pk >> 16) & 255], 1);
    }
    __syncthreads();
    {
        int v = cnt[t];
        ss[t] = v;
        __syncthreads();
        for (int d = 1; d < 256; d <<= 1) {
            int u = (t >= d) ? ss[t - d] : 0;
            __syncthreads();
            ss[t] += u;
            __syncthreads();
        }
        excl[t] = ss[t] - v;
    }
    __syncthreads();
    if (t < dmax) ptr[d0 + t] = bb + excl[t];
    if (b == NBUCK - 1 && t == 0) ptr[N_NODES] = N_EDGES;
    for (int i = t; i < n; i += 256) {
        unsigned pk = fits ? P[i] : bpairs[bb + i];
        int ld = (pk >> 16) & 255;
        int pos = bb + excl[ld] + atomicAdd(&cur[ld], 1);
        csr[pos] = (unsigned short)(pk & 0xFFFFu);
    }
}

// ---- MFMA GEMM (bf16x2 split, ~f32 accurate) + attention-logit epilogue ----
template <int H, int AF32>
__global__ __launch_bounds__(256) void gemm_mfma_kernel(const unsigned short* __restrict__ Ah,
                                                        const unsigned short* __restrict__ Al,
                                                        const float* __restrict__ Af,
                                                        const unsigned short* __restrict__ Bh,
                                                        const unsigned short* __restrict__ Bl,
                                                        const float* __restrict__ asrc,
                                                        const float* __restrict__ adst,
                                                        unsigned short* __restrict__ Hb,
                                                        float* __restrict__ als,
                                                        float* __restrict__ ald,
                                                        int nrows) {
    using bf16x8 = __attribute__((ext_vector_type(8))) short;
    using f32x4  = __attribute__((ext_vector_type(4))) float;
    const int lane = threadIdx.x & 63;
    const int wv = threadIdx.x >> 6;
    const int l15 = lane & 15;
    const int g = lane >> 4;
    const int lk = g * 8;
    const int rowbase = blockIdx.x * 128 + wv * 32;
    const int r0c = min(rowbase + l15, nrows - 1);
    const int r1c = min(rowbase + 16 + l15, nrows - 1);

    f32x4 acc[2][8];
    #pragma unroll
    for (int rt = 0; rt < 2; ++rt)
        #pragma unroll
        for (int ct = 0; ct < 8; ++ct) acc[rt][ct] = (f32x4){0.f, 0.f, 0.f, 0.f};

    #pragma unroll
    for (int kc = 0; kc < 4; ++kc) {
        const int ko = kc * 32 + lk;
        bf16x8 ah0, ah1, al0, al1;
        if constexpr (AF32) {
            const float* b0 = Af + (size_t)r0c * 128 + ko;
            const float* b1 = Af + (size_t)r1c * 128 + ko;
            float4 u0 = *(const float4*)b0, u1 = *(const float4*)(b0 + 4);
            float4 v0 = *(const float4*)b1, v1 = *(const float4*)(b1 + 4);
            float a0[8] = {u0.x, u0.y, u0.z, u0.w, u1.x, u1.y, u1.z, u1.w};
            float a1[8] = {v0.x, v0.y, v0.z, v0.w, v1.x, v1.y, v1.z, v1.w};
            #pragma unroll
            for (int i = 0; i < 8; ++i) {
                unsigned h0 = bf16rne(a0[i]);
                ah0[i] = (short)h0; al0[i] = (short)bf16rne(a0[i] - bf2f(h0));
                unsigned h1 = bf16rne(a1[i]);
                ah1[i] = (short)h1; al1[i] = (short)bf16rne(a1[i] - bf2f(h1));
            }
        } else {
            ah0 = *(const bf16x8*)(Ah + (size_t)(rowbase + l15) * 128 + ko);
            ah1 = *(const bf16x8*)(Ah + (size_t)(rowbase + 16 + l15) * 128 + ko);
            al0 = *(const bf16x8*)(Al + (size_t)(rowbase + l15) * 128 + ko);
            al1 = *(const bf16x8*)(Al + (size_t)(rowbase + 16 + l15) * 128 + ko);
        }
        #pragma unroll
        for (int ct = 0; ct < 8; ++ct) {
            bf16x8 bh = *(const bf16x8*)(Bh + (size_t)(ct * 16 + l15) * 128 + ko);
            bf16x8 bl = *(const bf16x8*)(Bl + (size_t)(ct * 16 + l15) * 128 + ko);
            acc[0][ct] = __builtin_amdgcn_mfma_f32_16x16x32_bf16(ah0, bh, acc[0][ct], 0, 0, 0);
            acc[0][ct] = __builtin_amdgcn_mfma_f32_16x16x32_bf16(ah0, bl, acc[0][ct], 0, 0, 0);
            acc[0][ct] = __builtin_amdgcn_mfma_f32_16x16x32_bf16(al0, bh, acc[0][ct], 0, 0, 0);
            acc[1][ct] = __builtin_amdgcn_mfma_f32_16x16x32_bf16(ah1, bh, acc[1][ct], 0, 0, 0);
            acc[1][ct] = __builtin_amdgcn_mfma_f32_16x16x32_bf16(ah1, bl, acc[1][ct], 0, 0, 0);
            acc[1][ct] = __builtin_amdgcn_mfma_f32_16x16x32_bf16(al1, bh, acc[1][ct], 0, 0, 0);
        }
    }

    float as8[8], ad8[8];
    #pragma unroll
    for (int ct = 0; ct < 8; ++ct) { as8[ct] = asrc[ct * 16 + l15]; ad8[ct] = adst[ct * 16 + l15]; }

    #pragma unroll
    for (int rt = 0; rt < 2; ++rt) {
        #pragma unroll
        for (int ct = 0; ct < 8; ++ct) {
            #pragma unroll
            for (int j = 0; j < 4; ++j) {
                int row = rowbase + rt * 16 + g * 4 + j;
                if (row < nrows)
                    Hb[(size_t)row * 128 + ct * 16 + l15] = (unsigned short)bf16rne(acc[rt][ct][j]);
            }
        }
        #pragma unroll
        for (int j = 0; j < 4; ++j) {
            int row = rowbase + rt * 16 + g * 4 + j;
            if (H == 2) {
                float sp0 = 0.f, sp1 = 0.f, dp0 = 0.f, dp1 = 0.f;
                #pragma unroll
                for (int ct = 0; ct < 4; ++ct) { sp0 += acc[rt][ct][j] * as8[ct]; dp0 += acc[rt][ct][j] * ad8[ct]; }
                #pragma unroll
                for (int ct = 4; ct < 8; ++ct) { sp1 += acc[rt][ct][j] * as8[ct]; dp1 += acc[rt][ct][j] * ad8[ct]; }
                #pragma unroll
                for (int off = 1; off < 16; off <<= 1) {
                    sp0 += __shfl_xor(sp0, off); sp1 += __shfl_xor(sp1, off);
                    dp0 += __shfl_xor(dp0, off); dp1 += __shfl_xor(dp1, off);
                }
                if (l15 == 0 && row < nrows) {
                    als[(size_t)row * 2]     = sp0; als[(size_t)row * 2 + 1] = sp1;
                    ald[(size_t)row * 2]     = dp0; ald[(size_t)row * 2 + 1] = dp1;
                }
            } else {
                float sp = 0.f, dp = 0.f;
                #pragma unroll
                for (int ct = 0; ct < 8; ++ct) { sp += acc[rt][ct][j] * as8[ct]; dp += acc[rt][ct][j] * ad8[ct]; }
                #pragma unroll
                for (int off = 1; off < 16; off <<= 1) {
                    sp += __shfl_xor(sp, off); dp += __shfl_xor(dp, off);
                }
                if (l15 == 0 && row < nrows) { als[row] = sp; ald[row] = dp; }
            }
        }
    }
}

// ---- fused softmax+gather v5: 2 dsts per wave (32 lanes each), uint2 gathers ----
// Per half-wave: lane owns 2 dwords (4 channels) of the 256B row; one gather inst
// now serves 2 edges (one per half). Keeps v2's 4-deep ILP and LDS-broadcast p.
template <int H, int DO_ELU, int BSPLIT>
__global__ __launch_bounds__(256) void aggregate_kernel(const unsigned short* __restrict__ Hb,
                                                        const float* __restrict__ als,
                                                        const float* __restrict__ aldv,
                                                        const int* __restrict__ ptr,
                                                        const unsigned short* __restrict__ csr,
                                                        const float* __restrict__ bias,
                                                        float* __restrict__ out,
                                                        unsigned short* __restrict__ oh,
                                                        unsigned short* __restrict__ ol) {
    __shared__ int   s_src[4][2][34];
    __shared__ float s_p[4][2][H][34];
    const uint2*  __restrict__ Hb2  = (const uint2*)Hb;      // row = 32 uint2
    const float2* __restrict__ als2 = (const float2*)als;
    const int w = threadIdx.x >> 6;
    const int lane = threadIdx.x & 63;
    const int half = lane >> 5;
    const int l31 = lane & 31;
    const int headc = (H == 2) ? (l31 >> 4) : 0;   // channels 4*l31.. all in one head

    int d = blockIdx.x * 8 + w * 2 + half;
    bool valid = d < N_NODES;
    int dv = valid ? d : N_NODES - 1;
    int beg = ptr[dv];
    int end = valid ? ptr[dv + 1] : beg;

    float ald0, ald1 = 0.f, es0, es1 = 0.f;
    if (H == 2) {
        float2 ta = ((const float2*)aldv)[(unsigned)dv];
        float2 ts = als2[(unsigned)dv];
        ald0 = ta.x; ald1 = ta.y;
        es0 = lrelu(ts.x + ald0); es1 = lrelu(ts.y + ald1);
    } else {
        ald0 = aldv[dv]; es0 = lrelu(als[dv] + ald0);
    }

    // phase 0: strided (32) logits + intra-half max
    int k0 = beg + l31;
    int src0 = dv;
    float e0 = -INFINITY, e1 = -INFINITY;
    if (k0 < end) {
        src0 = csr[k0];
        if (H == 2) {
            float2 t = als2[(unsigned)src0];
            e0 = lrelu(t.x + ald0); e1 = lrelu(t.y + ald1);
        } else e0 = lrelu(als[(unsigned)src0] + ald0);
    }
    float m0 = fmaxf(es0, e0);
    float m1 = (H == 2) ? fmaxf(es1, e1) : 0.f;
    for (int k = k0 + 32; k < end; k += 32) {
        int s = csr[k];
        if (H == 2) {
            float2 t = als2[(unsigned)s];
            m0 = fmaxf(m0, lrelu(t.x + ald0));
            m1 = fmaxf(m1, lrelu(t.y + ald1));
        } else m0 = fmaxf(m0, lrelu(als[(unsigned)s] + ald0));
    }
    #pragma unroll
    for (int off = 16; off; off >>= 1) {
        m0 = fmaxf(m0, __shfl_xor(m0, off));
        if (H == 2) m1 = fmaxf(m1, __shfl_xor(m1, off));
    }

    float l0 = 0.f, l1 = 0.f;
    float ac0[4], ac1[4], ac2[4], ac3[4];
    #pragma unroll
    for (int i = 0; i < 4; ++i) { ac0[i] = 0.f; ac1[i] = 0.f; ac2[i] = 0.f; ac3[i] = 0.f; }

    for (int tt = 0; ; ++tt) {
        int t0 = beg + tt * 32;
        int degT = end - t0;
        degT = degT < 0 ? 0 : (degT > 32 ? 32 : degT);
        int jm = max(degT, __shfl_xor(degT, 32));
        if (jm == 0) break;
        // phase A: lane -> edge t0+l31 of its half (p=0 padding beyond own cnt)
        {
            int k = t0 + l31;
            int s = dv;
            float p0v = 0.f, p1v = 0.f;
            if (k < end) {
                float f0, f1 = 0.f;
                if (tt == 0) { s = src0; f0 = e0; f1 = e1; }
                else {
                    s = csr[k];
                    if (H == 2) {
                        float2 t = als2[(unsigned)s];
                        f0 = lrelu(t.x + ald0); f1 = lrelu(t.y + ald1);
                    } else f0 = lrelu(als[(unsigned)s] + ald0);
                }
                p0v = __expf(f0 - m0);
                l0 += p0v;
                if (H == 2) { p1v = __expf(f1 - m1); l1 += p1v; }
            }
            s_src[w][half][l31] = s;
            s_p[w][half][0][l31] = p0v;
            if (H == 2) s_p[w][half][1][l31] = p1v;
        }
        // phase B: 4 independent uint2 gather chains; each inst covers both halves
        int j = 0;
        for (; j + 3 < jm; j += 4) {
            int sA = s_src[w][half][j],     sB = s_src[w][half][j + 1];
            int sC = s_src[w][half][j + 2], sD = s_src[w][half][j + 3];
            float pA = s_p[w][half][headc][j],     pB = s_p[w][half][headc][j + 1];
            float pC = s_p[w][half][headc][j + 2], pD = s_p[w][half][headc][j + 3];
            uint2 uA = Hb2[((unsigned)sA << 5) + l31];
            uint2 uB = Hb2[((unsigned)sB << 5) + l31];
            uint2 uC = Hb2[((unsigned)sC << 5) + l31];
            uint2 uD = Hb2[((unsigned)sD << 5) + l31];
            ac0[0] = fmaf(pA, __uint_as_float(uA.x << 16), ac0[0]);
            ac0[1] = fmaf(pA, __uint_as_float(uA.x & 0xffff0000u), ac0[1]);
            ac0[2] = fmaf(pA, __uint_as_float(uA.y << 16), ac0[2]);
            ac0[3] = fmaf(pA, __uint_as_float(uA.y & 0xffff0000u), ac0[3]);
            ac1[0] = fmaf(pB, __uint_as_float(uB.x << 16), ac1[0]);
            ac1[1] = fmaf(pB, __uint_as_float(uB.x & 0xffff0000u), ac1[1]);
            ac1[2] = fmaf(pB, __uint_as_float(uB.y << 16), ac1[2]);
            ac1[3] = fmaf(pB, __uint_as_float(uB.y & 0xffff0000u), ac1[3]);
            ac2[0] = fmaf(pC, __uint_as_float(uC.x << 16), ac2[0]);
            ac2[1] = fmaf(pC, __uint_as_float(uC.x & 0xffff0000u), ac2[1]);
            ac2[2] = fmaf(pC, __uint_as_float(uC.y << 16), ac2[2]);
            ac2[3] = fmaf(pC, __uint_as_float(uC.y & 0xffff0000u), ac2[3]);
            ac3[0] = fmaf(pD, __uint_as_float(uD.x << 16), ac3[0]);
            ac3[1] = fmaf(pD, __uint_as_float(uD.x & 0xffff0000u), ac3[1]);
            ac3[2] = fmaf(pD, __uint_as_float(uD.y << 16), ac3[2]);
            ac3[3] = fmaf(pD, __uint_as_float(uD.y & 0xffff0000u), ac3[3]);
        }
        for (; j < jm; ++j) {
            int sA = s_src[w][half][j];
            float pA = s_p[w][half][headc][j];
            uint2 uA = Hb2[((unsigned)sA << 5) + l31];
            ac0[0] = fmaf(pA, __uint_as_float(uA.x << 16), ac0[0]);
            ac0[1] = fmaf(pA, __uint_as_float(uA.x & 0xffff0000u), ac0[1]);
            ac0[2] = fmaf(pA, __uint_as_float(uA.y << 16), ac0[2]);
            ac0[3] = fmaf(pA, __uint_as_float(uA.y & 0xffff0000u), ac0[3]);
        }
    }

    float acc[4];
    #pragma unroll
    for (int i = 0; i < 4; ++i) acc[i] = (ac0[i] + ac1[i]) + (ac2[i] + ac3[i]);

    // self-loop
    float mh  = (headc == 0) ? m0 : m1;
    float esh = (headc == 0) ? es0 : es1;
    float psh = __expf(esh - mh);
    {
        uint2 u = Hb2[((unsigned)dv << 5) + l31];
        acc[0] = fmaf(psh, __uint_as_float(u.x << 16), acc[0]);
        acc[1] = fmaf(psh, __uint_as_float(u.x & 0xffff0000u), acc[1]);
        acc[2] = fmaf(psh, __uint_as_float(u.y << 16), acc[2]);
        acc[3] = fmaf(psh, __uint_as_float(u.y & 0xffff0000u), acc[3]);
    }
    // denominators (intra-half reduce)
    #pragma unroll
    for (int off = 16; off; off >>= 1) {
        l0 += __shfl_xor(l0, off);
        if (H == 2) l1 += __shfl_xor(l1, off);
    }
    float denom = ((headc == 0) ? l0 : l1) + psh;
    float inv = 1.f / (denom + 1e-16f);
    float4 b4 = *(const float4*)(bias + 4 * l31);
    float o0 = acc[0] * inv + b4.x;
    float o1 = acc[1] * inv + b4.y;
    float o2 = acc[2] * inv + b4.z;
    float o3 = acc[3] * inv + b4.w;
    if (DO_ELU) {
        o0 = o0 > 0.f ? o0 : __expf(o0) - 1.f;
        o1 = o1 > 0.f ? o1 : __expf(o1) - 1.f;
        o2 = o2 > 0.f ? o2 : __expf(o2) - 1.f;
        o3 = o3 > 0.f ? o3 : __expf(o3) - 1.f;
    }
    if (valid) {
        if (BSPLIT) {
            unsigned h0 = bf16rne(o0), h1 = bf16rne(o1), h2 = bf16rne(o2), h3 = bf16rne(o3);
            ushort4 sh; sh.x = h0; sh.y = h1; sh.z = h2; sh.w = h3;
            ushort4 sl;
            sl.x = bf16rne(o0 - bf2f(h0)); sl.y = bf16rne(o1 - bf2f(h1));
            sl.z = bf16rne(o2 - bf2f(h2)); sl.w = bf16rne(o3 - bf2f(h3));
            *(ushort4*)(oh + (size_t)dv * 128 + 4 * l31) = sh;
            *(ushort4*)(ol + (size_t)dv * 128 + 4 * l31) = sl;
        } else {
            *(float4*)(out + (size_t)dv * 128 + 4 * l31) = make_float4(o0, o1, o2, o3);
        }
    }
}

// ---------------- launch ----------------
extern "C" void kernel_launch(void* const* d_in, const int* in_sizes, int n_in,
                              void* d_out, int out_size, void* d_ws, size_t ws_size,
                              hipStream_t stream) {
    const float* x      = (const float*)d_in[0];
    const int*   ei     = (const int*)d_in[1];
    const float* W1     = (const float*)d_in[2];
    const float* a_src1 = (const float*)d_in[3];
    const float* a_dst1 = (const float*)d_in[4];
    const float* b1     = (const float*)d_in[5];
    const float* W2     = (const float*)d_in[6];
    const float* a_src2 = (const float*)d_in[7];
    const float* a_dst2 = (const float*)d_in[8];
    const float* b2     = (const float*)d_in[9];
    float* out = (float*)d_out;

    char* ws = (char*)d_ws;
    size_t off = 0;
    auto alloc = [&](size_t bytes) { void* p = ws + off; off += (bytes + 255) & ~(size_t)255; return p; };
    int*      ptr    = (int*)alloc((N_NODES + 1) * sizeof(int));
    int*      gbcnt  = (int*)alloc(NBUCK * sizeof(int));
    int*      bbase  = (int*)alloc((NBUCK + 1) * sizeof(int));
    int*      bcur   = (int*)alloc(NBUCK * sizeof(int));
    unsigned* bpairs = (unsigned*)alloc((size_t)N_EDGES * sizeof(unsigned));
    unsigned short* csr = (unsigned short*)alloc((size_t)N_EDGES * sizeof(unsigned short));
    unsigned short* x2h = (unsigned short*)alloc((size_t)NPAD * 128 * 2);
    unsigned short* x2l = (unsigned short*)alloc((size_t)NPAD * 128 * 2);
    unsigned short* hb  = (unsigned short*)alloc((size_t)N_NODES * 128 * 2);
    unsigned short* w1h = (unsigned short*)alloc(128 * 128 * 2);
    unsigned short* w1l = (unsigned short*)alloc(128 * 128 * 2);
    unsigned short* w2h = (unsigned short*)alloc(128 * 128 * 2);
    unsigned short* w2l = (unsigned short*)alloc(128 * 128 * 2);
    float* als    = (float*)alloc(N_NODES * 2 * sizeof(float));
    float* ald    = (float*)alloc(N_NODES * 2 * sizeof(float));

    // ---- CSR build (packed bucket sort; same graph both layers) ----
    zerobuf_kernel<<<1, 256, 0, stream>>>(gbcnt);
    bucketcount_kernel<<<256, 256, 0, stream>>>(ei, gbcnt);
    scan_convw_kernel<<<129, 256, 0, stream>>>(gbcnt, bbase, bcur, W1, w1h, w1l, W2, w2h, w2l);
    bucketscatter_kernel<<<(N_EDGES + CCHUNK - 1) / CCHUNK, 256, 0, stream>>>(ei, bcur, bpairs);
    csrfinalize_kernel<<<NBUCK, 256, 0, stream>>>(bpairs, bbase, ptr, csr);

    int gblocks = NPAD / 128;             // 391
    int wblocks = (N_NODES + 7) / 8;      // 8 dsts per block (4 waves x 2)

    // ---- layer 1 ----
    gemm_mfma_kernel<2, 1><<<gblocks, 256, 0, stream>>>(nullptr, nullptr, x, w1h, w1l,
                                                        a_src1, a_dst1, hb, als, ald, N_NODES);
    aggregate_kernel<2, 1, 1><<<wblocks, 256, 0, stream>>>(hb, als, ald, ptr, csr, b1,
                                                           nullptr, x2h, x2l);

    // ---- layer 2 ----
    gemm_mfma_kernel<1, 0><<<gblocks, 256, 0, stream>>>(x2h, x2l, nullptr, w2h, w2l,
                                                        a_src2, a_dst2, hb, als, ald, N_NODES);
    aggregate_kernel<1, 0, 0><<<wblocks, 256, 0, stream>>>(hb, als, ald, ptr, csr, b2,
                                                           out, nullptr, nullptr);
}

// Round 18
// 167.117 us; speedup vs baseline: 1.1646x; 1.0186x over previous
//
#include <hip/hip_runtime.h>
#include <hip/hip_bf16.h>
#include <math.h>

#define N_NODES 50000
#define NPAD 50048                      // 391 * 128
#define N_EDGES 800000
#define NEG_SLOPE 0.2f
#define NBUCK ((N_NODES + 255) / 256)   // 196 buckets of 256 dsts
#define CCHUNK 4096
#define DCAP 8192

__device__ inline float lrelu(float x) { return fmaxf(x, NEG_SLOPE * x); }

__device__ inline unsigned bf16rne(float f) {
    unsigned u = __float_as_uint(f);
    return (u + 0x7fffu + ((u >> 16) & 1u)) >> 16;
}
__device__ inline float bf2f(unsigned h) { return __uint_as_float(h << 16); }

// ---------------- CSR build pieces ----------------
__device__ __forceinline__ void count_body(int bx, const int* __restrict__ ei,
                                           int* __restrict__ gbcnt) {
    __shared__ int lc[NBUCK];
    for (int i = threadIdx.x; i < NBUCK; i += 256) lc[i] = 0;
    __syncthreads();
    for (int e = bx * 256 + threadIdx.x; e < N_EDGES; e += 256 * 256)
        atomicAdd(&lc[ei[N_EDGES + e] >> 8], 1);
    __syncthreads();
    for (int i = threadIdx.x; i < NBUCK; i += 256)
        if (lc[i]) atomicAdd(&gbcnt[i], lc[i]);
}

// blocks 0..127: W1/W2 transpose+bf16 split; blocks 128..383: bucket histogram
__global__ __launch_bounds__(256) void convw_count_kernel(const float* __restrict__ W1,
                                                          unsigned short* __restrict__ w1h,
                                                          unsigned short* __restrict__ w1l,
                                                          const float* __restrict__ W2,
                                                          unsigned short* __restrict__ w2h,
                                                          unsigned short* __restrict__ w2l,
                                                          const int* __restrict__ ei,
                                                          int* __restrict__ gbcnt) {
    int b = blockIdx.x;
    int t = threadIdx.x;
    if (b < 128) {
        int idx = b * 256 + t;
        const float* W = W1;
        unsigned short* th = w1h;
        unsigned short* tl = w1l;
        if (idx >= 128 * 128) { W = W2; th = w2h; tl = w2l; idx -= 128 * 128; }
        int c = idx >> 7, k = idx & 127;
        float v = W[(size_t)k * 128 + c];
        unsigned h = bf16rne(v);
        th[idx] = (unsigned short)h;
        tl[idx] = (unsigned short)bf16rne(v - bf2f(h));
    } else {
        count_body(b - 128, ei, gbcnt);
    }
}

__global__ __launch_bounds__(256) void bucketscan_kernel(const int* __restrict__ gbcnt,
                                                         int* __restrict__ bbase,
                                                         int* __restrict__ bcur) {
    __shared__ int ss[256];
    int t = threadIdx.x;
    int v = (t < NBUCK) ? gbcnt[t] : 0;
    ss[t] = v;
    __syncthreads();
    for (int d = 1; d < 256; d <<= 1) {
        int u = (t >= d) ? ss[t - d] : 0;
        __syncthreads();
        ss[t] += u;
        __syncthreads();
    }
    int excl = ss[t] - v;
    if (t < NBUCK) { bbase[t] = excl; bcur[t] = excl; }
    if (t == 0) bbase[NBUCK] = N_EDGES;
}

// pk = src | (dst<<16)
__global__ __launch_bounds__(256) void bucketscatter_kernel(const int* __restrict__ ei,
                                                            int* __restrict__ bcur,
                                                            unsigned* __restrict__ bpairs) {
    __shared__ int cnt[NBUCK], startl[NBUCK], baseg[NBUCK], cur2[NBUCK];
    __shared__ int ss[256];
    __shared__ unsigned stage[CCHUNK];
    int t = threadIdx.x;
    int e0 = blockIdx.x * CCHUNK;
    int nume = min(CCHUNK, N_EDGES - e0);
    for (int i = t; i < NBUCK; i += 256) { cnt[i] = 0; cur2[i] = 0; }
    __syncthreads();
    int src[CCHUNK / 256], dst[CCHUNK / 256];
    #pragma unroll
    for (int j = 0; j < CCHUNK / 256; ++j) {
        int idx = t + j * 256;
        if (idx < nume) {
            src[j] = ei[e0 + idx];
            dst[j] = ei[N_EDGES + e0 + idx];
            atomicAdd(&cnt[dst[j] >> 8], 1);
        } else dst[j] = -1;
    }
    __syncthreads();
    {
        int v = (t < NBUCK) ? cnt[t] : 0;
        ss[t] = v;
        __syncthreads();
        for (int d = 1; d < 256; d <<= 1) {
            int u = (t >= d) ? ss[t - d] : 0;
            __syncthreads();
            ss[t] += u;
            __syncthreads();
        }
        if (t < NBUCK) startl[t] = ss[t] - v;
    }
    __syncthreads();
    if (t < NBUCK && cnt[t] > 0) baseg[t] = atomicAdd(&bcur[t], cnt[t]);
    __syncthreads();
    #pragma unroll
    for (int j = 0; j < CCHUNK / 256; ++j) {
        if (dst[j] >= 0) {
            int b = dst[j] >> 8;
            int slot = startl[b] + atomicAdd(&cur2[b], 1);
            stage[slot] = (unsigned)src[j] | ((unsigned)dst[j] << 16);
        }
    }
    __syncthreads();
    for (int i = t; i < nume; i += 256) {
        unsigned pk = stage[i];
        int b = pk >> 24;
        bpairs[baseg[b] + (i - startl[b])] = pk;
    }
}

__global__ __launch_bounds__(256) void csrfinalize_kernel(const unsigned* __restrict__ bpairs,
                                                          const int* __restrict__ bbase,
                                                          int* __restrict__ ptr,
                                                          unsigned short* __restrict__ csr) {
    __shared__ int cnt[256], excl[256], cur[256];
    __shared__ int ss[256];
    __shared__ unsigned P[DCAP];
    int b = blockIdx.x, t = threadIdx.x;
    int bb = bbase[b], be = bbase[b + 1];
    int n = be - bb;
    int d0 = b << 8;
    int dmax = min(256, N_NODES - d0);
    bool fits = (n <= DCAP);
    cnt[t] = 0; cur[t] = 0;
    __syncthreads();
    for (int i = t; i < n; i += 256) {
        unsigned pk = bpairs[bb + i];
        if (fits) P[i] = pk;
        atomicAdd(&cnt[(pk >> 16) & 255], 1);
    }
    __syncthreads();
    {
        int v = cnt[t];
        ss[t] = v;
        __syncthreads();
        for (int d = 1; d < 256; d <<= 1) {
            int u = (t >= d) ? ss[t - d] : 0;
            __syncthreads();
            ss[t] += u;
            __syncthreads();
        }
        excl[t] = ss[t] - v;
    }
    __syncthreads();
    if (t < dmax) ptr[d0 + t] = bb + excl[t];
    if (b == NBUCK - 1 && t == 0) ptr[N_NODES] = N_EDGES;
    for (int i = t; i < n; i += 256) {
        unsigned pk = fits ? P[i] : bpairs[bb + i];
        int ld = (pk >> 16) & 255;
        int pos = bb + excl[ld] + atomicAdd(&cur[ld], 1);
        csr[pos] = (unsigned short)(pk & 0xFFFFu);
    }
}

// ---- MFMA GEMM body (bf16x2 split) + attention-logit epilogue ----
template <int H, int AF32>
__device__ __forceinline__ void gemm_body(int bx,
                                          const unsigned short* __restrict__ Ah,
                                          const unsigned short* __restrict__ Al,
                                          const float* __restrict__ Af,
                                          const unsigned short* __restrict__ Bh,
                                          const unsigned short* __restrict__ Bl,
                                          const float* __restrict__ asrc,
                                          const float* __restrict__ adst,
                                          unsigned short* __restrict__ Hb,
                                          float* __restrict__ als,
                                          float* __restrict__ ald,
                                          int nrows) {
    using bf16x8 = __attribute__((ext_vector_type(8))) short;
    using f32x4  = __attribute__((ext_vector_type(4))) float;
    const int lane = threadIdx.x & 63;
    const int wv = threadIdx.x >> 6;
    const int l15 = lane & 15;
    const int g = lane >> 4;
    const int lk = g * 8;
    const int rowbase = bx * 128 + wv * 32;
    const int r0c = min(rowbase + l15, nrows - 1);
    const int r1c = min(rowbase + 16 + l15, nrows - 1);

    f32x4 acc[2][8];
    #pragma unroll
    for (int rt = 0; rt < 2; ++rt)
        #pragma unroll
        for (int ct = 0; ct < 8; ++ct) acc[rt][ct] = (f32x4){0.f, 0.f, 0.f, 0.f};

    #pragma unroll
    for (int kc = 0; kc < 4; ++kc) {
        const int ko = kc * 32 + lk;
        bf16x8 ah0, ah1, al0, al1;
        if constexpr (AF32) {
            const float* b0 = Af + (size_t)r0c * 128 + ko;
            const float* b1 = Af + (size_t)r1c * 128 + ko;
            float4 u0 = *(const float4*)b0, u1 = *(const float4*)(b0 + 4);
            float4 v0 = *(const float4*)b1, v1 = *(const float4*)(b1 + 4);
            float a0[8] = {u0.x, u0.y, u0.z, u0.w, u1.x, u1.y, u1.z, u1.w};
            float a1[8] = {v0.x, v0.y, v0.z, v0.w, v1.x, v1.y, v1.z, v1.w};
            #pragma unroll
            for (int i = 0; i < 8; ++i) {
                unsigned h0 = bf16rne(a0[i]);
                ah0[i] = (short)h0; al0[i] = (short)bf16rne(a0[i] - bf2f(h0));
                unsigned h1 = bf16rne(a1[i]);
                ah1[i] = (short)h1; al1[i] = (short)bf16rne(a1[i] - bf2f(h1));
            }
        } else {
            ah0 = *(const bf16x8*)(Ah + (size_t)(rowbase + l15) * 128 + ko);
            ah1 = *(const bf16x8*)(Ah + (size_t)(rowbase + 16 + l15) * 128 + ko);
            al0 = *(const bf16x8*)(Al + (size_t)(rowbase + l15) * 128 + ko);
            al1 = *(const bf16x8*)(Al + (size_t)(rowbase + 16 + l15) * 128 + ko);
        }
        #pragma unroll
        for (int ct = 0; ct < 8; ++ct) {
            bf16x8 bh = *(const bf16x8*)(Bh + (size_t)(ct * 16 + l15) * 128 + ko);
            bf16x8 bl = *(const bf16x8*)(Bl + (size_t)(ct * 16 + l15) * 128 + ko);
            acc[0][ct] = __builtin_amdgcn_mfma_f32_16x16x32_bf16(ah0, bh, acc[0][ct], 0, 0, 0);
            acc[0][ct] = __builtin_amdgcn_mfma_f32_16x16x32_bf16(ah0, bl, acc[0][ct], 0, 0, 0);
            acc[0][ct] = __builtin_amdgcn_mfma_f32_16x16x32_bf16(al0, bh, acc[0][ct], 0, 0, 0);
            acc[1][ct] = __builtin_amdgcn_mfma_f32_16x16x32_bf16(ah1, bh, acc[1][ct], 0, 0, 0);
            acc[1][ct] = __builtin_amdgcn_mfma_f32_16x16x32_bf16(ah1, bl, acc[1][ct], 0, 0, 0);
            acc[1][ct] = __builtin_amdgcn_mfma_f32_16x16x32_bf16(al1, bh, acc[1][ct], 0, 0, 0);
        }
    }

    float as8[8], ad8[8];
    #pragma unroll
    for (int ct = 0; ct < 8; ++ct) { as8[ct] = asrc[ct * 16 + l15]; ad8[ct] = adst[ct * 16 + l15]; }

    #pragma unroll
    for (int rt = 0; rt < 2; ++rt) {
        #pragma unroll
        for (int ct = 0; ct < 8; ++ct) {
            #pragma unroll
            for (int j = 0; j < 4; ++j) {
                int row = rowbase + rt * 16 + g * 4 + j;
                if (row < nrows)
                    Hb[(size_t)row * 128 + ct * 16 + l15] = (unsigned short)bf16rne(acc[rt][ct][j]);
            }
        }
        #pragma unroll
        for (int j = 0; j < 4; ++j) {
            int row = rowbase + rt * 16 + g * 4 + j;
            if (H == 2) {
                float sp0 = 0.f, sp1 = 0.f, dp0 = 0.f, dp1 = 0.f;
                #pragma unroll
                for (int ct = 0; ct < 4; ++ct) { sp0 += acc[rt][ct][j] * as8[ct]; dp0 += acc[rt][ct][j] * ad8[ct]; }
                #pragma unroll
                for (int ct = 4; ct < 8; ++ct) { sp1 += acc[rt][ct][j] * as8[ct]; dp1 += acc[rt][ct][j] * ad8[ct]; }
                #pragma unroll
                for (int off = 1; off < 16; off <<= 1) {
                    sp0 += __shfl_xor(sp0, off); sp1 += __shfl_xor(sp1, off);
                    dp0 += __shfl_xor(dp0, off); dp1 += __shfl_xor(dp1, off);
                }
                if (l15 == 0 && row < nrows) {
                    als[(size_t)row * 2]     = sp0; als[(size_t)row * 2 + 1] = sp1;
                    ald[(size_t)row * 2]     = dp0; ald[(size_t)row * 2 + 1] = dp1;
                }
            } else {
                float sp = 0.f, dp = 0.f;
                #pragma unroll
                for (int ct = 0; ct < 8; ++ct) { sp += acc[rt][ct][j] * as8[ct]; dp += acc[rt][ct][j] * ad8[ct]; }
                #pragma unroll
                for (int off = 1; off < 16; off <<= 1) {
                    sp += __shfl_xor(sp, off); dp += __shfl_xor(dp, off);
                }
                if (l15 == 0 && row < nrows) { als[row] = sp; ald[row] = dp; }
            }
        }
    }
}

template <int H, int AF32>
__global__ __launch_bounds__(256) void gemm_mfma_kernel(const unsigned short* __restrict__ Ah,
                                                        const unsigned short* __restrict__ Al,
                                                        const float* __restrict__ Af,
                                                        const unsigned short* __restrict__ Bh,
                                                        const unsigned short* __restrict__ Bl,
                                                        const float* __restrict__ asrc,
                                                        const float* __restrict__ adst,
                                                        unsigned short* __restrict__ Hb,
                                                        float* __restrict__ als,
                                                        float* __restrict__ ald,
                                                        int nrows) {
    gemm_body<H, AF32>(blockIdx.x, Ah, Al, Af, Bh, Bl, asrc, adst, Hb, als, ald, nrows);
}

// fused: layer-1 GEMM (blocks 0..gemmblocks-1) + bucketscatter prep is NOT here;
// blocks gemmblocks.. run the scan (1 block). GEMM ∥ scan overlap.
template <int H, int AF32>
__global__ __launch_bounds__(256) void gemm_scan_kernel(const float* __restrict__ Af,
                                                        const unsigned short* __restrict__ Bh,
                                                        const unsigned short* __restrict__ Bl,
                                                        const float* __restrict__ asrc,
                                                        const float* __restrict__ adst,
                                                        unsigned short* __restrict__ Hb,
                                                        float* __restrict__ als,
                                                        float* __restrict__ ald,
                                                        int nrows,
                                                        const int* __restrict__ gbcnt,
                                                        int* __restrict__ bbase,
                                                        int* __restrict__ bcur,
                                                        int gemmblocks) {
    if ((int)blockIdx.x < gemmblocks) {
        gemm_body<H, AF32>(blockIdx.x, nullptr, nullptr, Af, Bh, Bl, asrc, adst, Hb, als, ald, nrows);
    } else {
        __shared__ int ss[256];
        int t = threadIdx.x;
        int v = (t < NBUCK) ? gbcnt[t] : 0;
        ss[t] = v;
        __syncthreads();
        for (int d = 1; d < 256; d <<= 1) {
            int u = (t >= d) ? ss[t - d] : 0;
            __syncthreads();
            ss[t] += u;
            __syncthreads();
        }
        int excl = ss[t] - v;
        if (t < NBUCK) { bbase[t] = excl; bcur[t] = excl; }
        if (t == 0) bbase[NBUCK] = N_EDGES;
    }
}

// ---- fused softmax+gather v5 ----
template <int H, int DO_ELU, int BSPLIT>
__global__ __launch_bounds__(256) void aggregate_kernel(const unsigned short* __restrict__ Hb,
                                                        const float* __restrict__ als,
                                                        const float* __restrict__ aldv,
                                                        const int* __restrict__ ptr,
                                                        const unsigned short* __restrict__ csr,
                                                        const float* __restrict__ bias,
                                                        float* __restrict__ out,
                                                        unsigned short* __restrict__ oh,
                                                        unsigned short* __restrict__ ol) {
    __shared__ int   s_src[4][2][34];
    __shared__ float s_p[4][2][H][34];
    const uint2*  __restrict__ Hb2  = (const uint2*)Hb;
    const float2* __restrict__ als2 = (const float2*)als;
    const int w = threadIdx.x >> 6;
    const int lane = threadIdx.x & 63;
    const int half = lane >> 5;
    const int l31 = lane & 31;
    const int headc = (H == 2) ? (l31 >> 4) : 0;

    int d = blockIdx.x * 8 + w * 2 + half;
    bool valid = d < N_NODES;
    int dv = valid ? d : N_NODES - 1;
    int beg = ptr[dv];
    int end = valid ? ptr[dv + 1] : beg;

    float ald0, ald1 = 0.f, es0, es1 = 0.f;
    if (H == 2) {
        float2 ta = ((const float2*)aldv)[(unsigned)dv];
        float2 ts = als2[(unsigned)dv];
        ald0 = ta.x; ald1 = ta.y;
        es0 = lrelu(ts.x + ald0); es1 = lrelu(ts.y + ald1);
    } else {
        ald0 = aldv[dv]; es0 = lrelu(als[dv] + ald0);
    }

    int k0 = beg + l31;
    int src0 = dv;
    float e0 = -INFINITY, e1 = -INFINITY;
    if (k0 < end) {
        src0 = csr[k0];
        if (H == 2) {
            float2 t = als2[(unsigned)src0];
            e0 = lrelu(t.x + ald0); e1 = lrelu(t.y + ald1);
        } else e0 = lrelu(als[(unsigned)src0] + ald0);
    }
    float m0 = fmaxf(es0, e0);
    float m1 = (H == 2) ? fmaxf(es1, e1) : 0.f;
    for (int k = k0 + 32; k < end; k += 32) {
        int s = csr[k];
        if (H == 2) {
            float2 t = als2[(unsigned)s];
            m0 = fmaxf(m0, lrelu(t.x + ald0));
            m1 = fmaxf(m1, lrelu(t.y + ald1));
        } else m0 = fmaxf(m0, lrelu(als[(unsigned)s] + ald0));
    }
    #pragma unroll
    for (int off = 16; off; off >>= 1) {
        m0 = fmaxf(m0, __shfl_xor(m0, off));
        if (H == 2) m1 = fmaxf(m1, __shfl_xor(m1, off));
    }

    float l0 = 0.f, l1 = 0.f;
    float ac0[4], ac1[4], ac2[4], ac3[4];
    #pragma unroll
    for (int i = 0; i < 4; ++i) { ac0[i] = 0.f; ac1[i] = 0.f; ac2[i] = 0.f; ac3[i] = 0.f; }

    for (int tt = 0; ; ++tt) {
        int t0 = beg + tt * 32;
        int degT = end - t0;
        degT = degT < 0 ? 0 : (degT > 32 ? 32 : degT);
        int jm = max(degT, __shfl_xor(degT, 32));
        if (jm == 0) break;
        {
            int k = t0 + l31;
            int s = dv;
            float p0v = 0.f, p1v = 0.f;
            if (k < end) {
                float f0, f1 = 0.f;
                if (tt == 0) { s = src0; f0 = e0; f1 = e1; }
                else {
                    s = csr[k];
                    if (H == 2) {
                        float2 t = als2[(unsigned)s];
                        f0 = lrelu(t.x + ald0); f1 = lrelu(t.y + ald1);
                    } else f0 = lrelu(als[(unsigned)s] + ald0);
                }
                p0v = __expf(f0 - m0);
                l0 += p0v;
                if (H == 2) { p1v = __expf(f1 - m1); l1 += p1v; }
            }
            s_src[w][half][l31] = s;
            s_p[w][half][0][l31] = p0v;
            if (H == 2) s_p[w][half][1][l31] = p1v;
        }
        int j = 0;
        for (; j + 3 < jm; j += 4) {
            int sA = s_src[w][half][j],     sB = s_src[w][half][j + 1];
            int sC = s_src[w][half][j + 2], sD = s_src[w][half][j + 3];
            float pA = s_p[w][half][headc][j],     pB = s_p[w][half][headc][j + 1];
            float pC = s_p[w][half][headc][j + 2], pD = s_p[w][half][headc][j + 3];
            uint2 uA = Hb2[((unsigned)sA << 5) + l31];
            uint2 uB = Hb2[((unsigned)sB << 5) + l31];
            uint2 uC = Hb2[((unsigned)sC << 5) + l31];
            uint2 uD = Hb2[((unsigned)sD << 5) + l31];
            ac0[0] = fmaf(pA, __uint_as_float(uA.x << 16), ac0[0]);
            ac0[1] = fmaf(pA, __uint_as_float(uA.x & 0xffff0000u), ac0[1]);
            ac0[2] = fmaf(pA, __uint_as_float(uA.y << 16), ac0[2]);
            ac0[3] = fmaf(pA, __uint_as_float(uA.y & 0xffff0000u), ac0[3]);
            ac1[0] = fmaf(pB, __uint_as_float(uB.x << 16), ac1[0]);
            ac1[1] = fmaf(pB, __uint_as_float(uB.x & 0xffff0000u), ac1[1]);
            ac1[2] = fmaf(pB, __uint_as_float(uB.y << 16), ac1[2]);
            ac1[3] = fmaf(pB, __uint_as_float(uB.y & 0xffff0000u), ac1[3]);
            ac2[0] = fmaf(pC, __uint_as_float(uC.x << 16), ac2[0]);
            ac2[1] = fmaf(pC, __uint_as_float(uC.x & 0xffff0000u), ac2[1]);
            ac2[2] = fmaf(pC, __uint_as_float(uC.y << 16), ac2[2]);
            ac2[3] = fmaf(pC, __uint_as_float(uC.y & 0xffff0000u), ac2[3]);
            ac3[0] = fmaf(pD, __uint_as_float(uD.x << 16), ac3[0]);
            ac3[1] = fmaf(pD, __uint_as_float(uD.x & 0xffff0000u), ac3[1]);
            ac3[2] = fmaf(pD, __uint_as_float(uD.y << 16), ac3[2]);
            ac3[3] = fmaf(pD, __uint_as_float(uD.y & 0xffff0000u), ac3[3]);
        }
        for (; j < jm; ++j) {
            int sA = s_src[w][half][j];
            float pA = s_p[w][half][headc][j];
            uint2 uA = Hb2[((unsigned)sA << 5) + l31];
            ac0[0] = fmaf(pA, __uint_as_float(uA.x << 16), ac0[0]);
            ac0[1] = fmaf(pA, __uint_as_float(uA.x & 0xffff0000u), ac0[1]);
            ac0[2] = fmaf(pA, __uint_as_float(uA.y << 16), ac0[2]);
            ac0[3] = fmaf(pA, __uint_as_float(uA.y & 0xffff0000u), ac0[3]);
        }
    }

    float acc[4];
    #pragma unroll
    for (int i = 0; i < 4; ++i) acc[i] = (ac0[i] + ac1[i]) + (ac2[i] + ac3[i]);

    float mh  = (headc == 0) ? m0 : m1;
    float esh = (headc == 0) ? es0 : es1;
    float psh = __expf(esh - mh);
    {
        uint2 u = Hb2[((unsigned)dv << 5) + l31];
        acc[0] = fmaf(psh, __uint_as_float(u.x << 16), acc[0]);
        acc[1] = fmaf(psh, __uint_as_float(u.x & 0xffff0000u), acc[1]);
        acc[2] = fmaf(psh, __uint_as_float(u.y << 16), acc[2]);
        acc[3] = fmaf(psh, __uint_as_float(u.y & 0xffff0000u), acc[3]);
    }
    #pragma unroll
    for (int off = 16; off; off >>= 1) {
        l0 += __shfl_xor(l0, off);
        if (H == 2) l1 += __shfl_xor(l1, off);
    }
    float denom = ((headc == 0) ? l0 : l1) + psh;
    float inv = 1.f / (denom + 1e-16f);
    float4 b4 = *(const float4*)(bias + 4 * l31);
    float o0 = acc[0] * inv + b4.x;
    float o1 = acc[1] * inv + b4.y;
    float o2 = acc[2] * inv + b4.z;
    float o3 = acc[3] * inv + b4.w;
    if (DO_ELU) {
        o0 = o0 > 0.f ? o0 : __expf(o0) - 1.f;
        o1 = o1 > 0.f ? o1 : __expf(o1) - 1.f;
        o2 = o2 > 0.f ? o2 : __expf(o2) - 1.f;
        o3 = o3 > 0.f ? o3 : __expf(o3) - 1.f;
    }
    if (valid) {
        if (BSPLIT) {
            unsigned h0 = bf16rne(o0), h1 = bf16rne(o1), h2 = bf16rne(o2), h3 = bf16rne(o3);
            ushort4 sh; sh.x = h0; sh.y = h1; sh.z = h2; sh.w = h3;
            ushort4 sl;
            sl.x = bf16rne(o0 - bf2f(h0)); sl.y = bf16rne(o1 - bf2f(h1));
            sl.z = bf16rne(o2 - bf2f(h2)); sl.w = bf16rne(o3 - bf2f(h3));
            *(ushort4*)(oh + (size_t)dv * 128 + 4 * l31) = sh;
            *(ushort4*)(ol + (size_t)dv * 128 + 4 * l31) = sl;
        } else {
            *(float4*)(out + (size_t)dv * 128 + 4 * l31) = make_float4(o0, o1, o2, o3);
        }
    }
}

// ---------------- launch ----------------
extern "C" void kernel_launch(void* const* d_in, const int* in_sizes, int n_in,
                              void* d_out, int out_size, void* d_ws, size_t ws_size,
                              hipStream_t stream) {
    const float* x      = (const float*)d_in[0];
    const int*   ei     = (const int*)d_in[1];
    const float* W1     = (const float*)d_in[2];
    const float* a_src1 = (const float*)d_in[3];
    const float* a_dst1 = (const float*)d_in[4];
    const float* b1     = (const float*)d_in[5];
    const float* W2     = (const float*)d_in[6];
    const float* a_src2 = (const float*)d_in[7];
    const float* a_dst2 = (const float*)d_in[8];
    const float* b2     = (const float*)d_in[9];
    float* out = (float*)d_out;

    char* ws = (char*)d_ws;
    size_t off = 0;
    auto alloc = [&](size_t bytes) { void* p = ws + off; off += (bytes + 255) & ~(size_t)255; return p; };
    int*      ptr    = (int*)alloc((N_NODES + 1) * sizeof(int));
    int*      gbcnt  = (int*)alloc(NBUCK * sizeof(int));
    int*      bbase  = (int*)alloc((NBUCK + 1) * sizeof(int));
    int*      bcur   = (int*)alloc(NBUCK * sizeof(int));
    unsigned* bpairs = (unsigned*)alloc((size_t)N_EDGES * sizeof(unsigned));
    unsigned short* csr = (unsigned short*)alloc((size_t)N_EDGES * sizeof(unsigned short));
    unsigned short* x2h = (unsigned short*)alloc((size_t)NPAD * 128 * 2);
    unsigned short* x2l = (unsigned short*)alloc((size_t)NPAD * 128 * 2);
    unsigned short* hb  = (unsigned short*)alloc((size_t)N_NODES * 128 * 2);
    unsigned short* w1h = (unsigned short*)alloc(128 * 128 * 2);
    unsigned short* w1l = (unsigned short*)alloc(128 * 128 * 2);
    unsigned short* w2h = (unsigned short*)alloc(128 * 128 * 2);
    unsigned short* w2l = (unsigned short*)alloc(128 * 128 * 2);
    float* als    = (float*)alloc(N_NODES * 2 * sizeof(float));
    float* ald    = (float*)alloc(N_NODES * 2 * sizeof(float));

    int gblocks = NPAD / 128;             // 391
    int wblocks = (N_NODES + 7) / 8;

    hipMemsetAsync(gbcnt, 0, NBUCK * sizeof(int), stream);
    // convw (W splits) + bucket histogram fused: both only read inputs
    convw_count_kernel<<<128 + 256, 256, 0, stream>>>(W1, w1h, w1l, W2, w2h, w2l, ei, gbcnt);
    // layer-1 GEMM (needs w1h/w1l) fused with bucket scan (needs gbcnt)
    gemm_scan_kernel<2, 1><<<gblocks + 1, 256, 0, stream>>>(x, w1h, w1l, a_src1, a_dst1,
                                                            hb, als, ald, N_NODES,
                                                            gbcnt, bbase, bcur, gblocks);
    // scatter (needs bcur) — overlaps nothing, but gemm-1 already done in parallel
    bucketscatter_kernel<<<(N_EDGES + CCHUNK - 1) / CCHUNK, 256, 0, stream>>>(ei, bcur, bpairs);
    csrfinalize_kernel<<<NBUCK, 256, 0, stream>>>(bpairs, bbase, ptr, csr);

    // ---- layer 1 aggregate ----
    aggregate_kernel<2, 1, 1><<<wblocks, 256, 0, stream>>>(hb, als, ald, ptr, csr, b1,
                                                           nullptr, x2h, x2l);
    // ---- layer 2 ----
    gemm_mfma_kernel<1, 0><<<gblocks, 256, 0, stream>>>(x2h, x2l, nullptr, w2h, w2l,
                                                        a_src2, a_dst2, hb, als, ald, N_NODES);
    aggregate_kernel<1, 0, 0><<<wblocks, 256, 0, stream>>>(hb, als, ald, ptr, csr, b2,
                                                           out, nullptr, nullptr);
}